// Round 3
// baseline (920.065 us; speedup 1.0000x reference)
//
#include <hip/hip_runtime.h>
#include <math.h>

#define NFEAT 300
#define HID 32
#define NCLS 10

__global__ void k_init_deg(float* __restrict__ deg, int n) {
    int i = blockIdx.x * 256 + threadIdx.x;
    if (i < n) deg[i] = 1.0f;  // self-loop contributes 1
}

__global__ void k_count_deg(const int* __restrict__ ei, int E, float* __restrict__ deg) {
    int i = blockIdx.x * 256 + threadIdx.x;
    if (i < E) atomicAdd(deg + ei[E + i], 1.0f);  // dst side
}

__global__ void k_rsqrt(float* __restrict__ deg, int n) {
    int i = blockIdx.x * 256 + threadIdx.x;
    if (i < n) deg[i] = rsqrtf(deg[i]);
}

// h1[n][k] = sum_j x[n][j] * W1[j][k]; block = 8 nodes x 32 feats
__global__ __launch_bounds__(256) void k_gemm1(const float* __restrict__ x,
                                               const float* __restrict__ W1,
                                               float* __restrict__ h1, int n) {
    __shared__ float Ws[NFEAT * HID];
    for (int i = threadIdx.x; i < NFEAT * HID; i += 256) Ws[i] = W1[i];
    __syncthreads();
    int node = blockIdx.x * 8 + (threadIdx.x >> 5);
    int k = threadIdx.x & 31;
    if (node >= n) return;
    const float4* xr = reinterpret_cast<const float4*>(x + (size_t)node * NFEAT);
    float acc = 0.f;
#pragma unroll 5
    for (int j4 = 0; j4 < NFEAT / 4; ++j4) {
        float4 v = xr[j4];
        const float* w = Ws + (j4 * 4) * HID + k;
        acc = fmaf(v.x, w[0], acc);
        acc = fmaf(v.y, w[HID], acc);
        acc = fmaf(v.z, w[2 * HID], acc);
        acc = fmaf(v.w, w[3 * HID], acc);
    }
    h1[(size_t)node * HID + k] = acc;
}

__global__ void k_self1(const float* __restrict__ h1, const float* __restrict__ dinv,
                        float* __restrict__ agg, int n) {
    int i = blockIdx.x * 256 + threadIdx.x;  // over n*HID
    if (i >= n * HID) return;
    float d = dinv[i >> 5];
    agg[i] = h1[i] * d * d;
}

__global__ void k_scat1(const int* __restrict__ ei, int E,
                        const float* __restrict__ h1, const float* __restrict__ dinv,
                        float* __restrict__ agg) {
    long long t = (long long)blockIdx.x * 256 + threadIdx.x;
    if (t >= (long long)E * HID) return;
    int e = (int)(t >> 5);
    int k = (int)(t & 31);
    int s = ei[e];
    int d = ei[E + e];
    float w = dinv[s] * dinv[d];
    atomicAdd(agg + (size_t)d * HID + k, h1[(size_t)s * HID + k] * w);
}

__global__ void k_act(const float* __restrict__ agg, const float* __restrict__ b1,
                      float* __restrict__ h2, int n) {
    int i = blockIdx.x * 256 + threadIdx.x;
    if (i >= n * HID) return;
    h2[i] = tanhf(agg[i] + b1[i & 31]);
}

// g[n][c] = sum_k h2[n][k] * W2[k][c]
__global__ __launch_bounds__(256) void k_gemm2(const float* __restrict__ h2,
                                               const float* __restrict__ W2,
                                               float* __restrict__ g, int n) {
    __shared__ float Ws[HID * NCLS];
    for (int i = threadIdx.x; i < HID * NCLS; i += 256) Ws[i] = W2[i];  // 320 elems!
    __syncthreads();
    int t = blockIdx.x * 256 + threadIdx.x;
    if (t >= n * NCLS) return;
    int node = t / NCLS, c = t % NCLS;
    const float* hr = h2 + (size_t)node * HID;
    float acc = 0.f;
#pragma unroll
    for (int k = 0; k < HID; ++k) acc = fmaf(hr[k], Ws[k * NCLS + c], acc);
    g[t] = acc;
}

__global__ void k_self2(const float* __restrict__ g, const float* __restrict__ dinv,
                        float* __restrict__ agg, int n) {
    int i = blockIdx.x * 256 + threadIdx.x;  // over n*NCLS
    if (i >= n * NCLS) return;
    float d = dinv[i / NCLS];
    agg[i] = g[i] * d * d;
}

__global__ void k_scat2(const int* __restrict__ ei, int E,
                        const float* __restrict__ g, const float* __restrict__ dinv,
                        float* __restrict__ agg) {
    long long t = (long long)blockIdx.x * 256 + threadIdx.x;
    if (t >= (long long)E * NCLS) return;
    int e = (int)(t / NCLS);
    int c = (int)(t % NCLS);
    int s = ei[e];
    int d = ei[E + e];
    float w = dinv[s] * dinv[d];
    atomicAdd(agg + (size_t)d * NCLS + c, g[(size_t)s * NCLS + c] * w);
}

__global__ void k_lsm(const float* __restrict__ agg, const float* __restrict__ b2,
                      float* __restrict__ out, int n) {
    int node = blockIdx.x * 256 + threadIdx.x;
    if (node >= n) return;
    float v[NCLS];
    float m = -1e30f;
#pragma unroll
    for (int c = 0; c < NCLS; ++c) {
        v[c] = agg[node * NCLS + c] + b2[c];
        m = fmaxf(m, v[c]);
    }
    float s = 0.f;
#pragma unroll
    for (int c = 0; c < NCLS; ++c) s += expf(v[c] - m);
    float ls = logf(s);
#pragma unroll
    for (int c = 0; c < NCLS; ++c) out[node * NCLS + c] = v[c] - m - ls;
}

extern "C" void kernel_launch(void* const* d_in, const int* in_sizes, int n_in,
                              void* d_out, int out_size, void* d_ws, size_t ws_size,
                              hipStream_t stream) {
    const float* x  = (const float*)d_in[0];
    const int*   ei = (const int*)d_in[1];   // harness delivers integers as int32
    const float* W1 = (const float*)d_in[2];
    const float* b1 = (const float*)d_in[3];
    const float* W2 = (const float*)d_in[4];
    const float* b2 = (const float*)d_in[5];
    float* out = (float*)d_out;

    const int N = in_sizes[0] / NFEAT;   // 100000
    const int E = in_sizes[1] / 2;       // 3200000

    float* ws   = (float*)d_ws;
    float* dinv = ws;                       // N floats (deg -> dinv in place)
    float* h1   = ws + 102400;              // N*HID (reused as h2 after act)
    float* agg1 = h1 + (size_t)N * HID;     // N*HID (reused as g after act)
    float* g    = agg1;                     // alias: agg1 is dead once act consumed it
    float* agg2 = out;                      // d_out doubles as layer-2 accumulator

    dim3 B(256);
    k_init_deg<<<(N + 255) / 256, B, 0, stream>>>(dinv, N);
    k_count_deg<<<(E + 255) / 256, B, 0, stream>>>(ei, E, dinv);
    k_rsqrt<<<(N + 255) / 256, B, 0, stream>>>(dinv, N);

    k_gemm1<<<(N + 7) / 8, B, 0, stream>>>(x, W1, h1, N);
    k_self1<<<(N * HID + 255) / 256, B, 0, stream>>>(h1, dinv, agg1, N);
    long long t1 = (long long)E * HID;
    k_scat1<<<(unsigned)((t1 + 255) / 256), B, 0, stream>>>(ei, E, h1, dinv, agg1);

    k_act<<<(N * HID + 255) / 256, B, 0, stream>>>(agg1, b1, h1, N);
    k_gemm2<<<(N * NCLS + 255) / 256, B, 0, stream>>>(h1, W2, g, N);
    k_self2<<<(N * NCLS + 255) / 256, B, 0, stream>>>(g, dinv, agg2, N);
    long long t2 = (long long)E * NCLS;
    k_scat2<<<(unsigned)((t2 + 255) / 256), B, 0, stream>>>(ei, E, g, dinv, agg2);

    k_lsm<<<(N + 255) / 256, B, 0, stream>>>(agg2, b2, out, N);
}

// Round 4
// 806.712 us; speedup vs baseline: 1.1405x; 1.1405x over previous
//
#include <hip/hip_runtime.h>
#include <math.h>
#include <float.h>

#define NFEAT 300
#define HID 32
#define NCLS 10

__global__ void k_zero_i(int* __restrict__ p, int n) {
    int i = blockIdx.x * 256 + threadIdx.x;
    if (i < n) p[i] = 0;
}

__global__ void k_hist(const int* __restrict__ ei, int E, int* __restrict__ deg) {
    int i = blockIdx.x * 256 + threadIdx.x;
    if (i < E) atomicAdd(deg + ei[E + i], 1);  // dst side
}

// per-block (256-wide) partial sums of deg
__global__ void k_scan_part(const int* __restrict__ deg, int n, int* __restrict__ bsum) {
    __shared__ int s[256];
    int i = blockIdx.x * 256 + threadIdx.x;
    s[threadIdx.x] = (i < n) ? deg[i] : 0;
    __syncthreads();
    for (int off = 128; off > 0; off >>= 1) {
        if (threadIdx.x < off) s[threadIdx.x] += s[threadIdx.x + off];
        __syncthreads();
    }
    if (threadIdx.x == 0) bsum[blockIdx.x] = s[0];
}

// single-block exclusive scan of bsum[0..m), m <= 1024
__global__ void k_scan_top(int* __restrict__ bsum, int m) {
    __shared__ int s[1024];
    int tid = threadIdx.x;
    int v = (tid < m) ? bsum[tid] : 0;
    s[tid] = v;
    __syncthreads();
    for (int off = 1; off < 1024; off <<= 1) {
        int t = (tid >= off) ? s[tid - off] : 0;
        __syncthreads();
        s[tid] += t;
        __syncthreads();
    }
    if (tid < m) bsum[tid] = s[tid] - v;  // exclusive
}

// rowptr/cursor/dinv from deg + scanned block offsets
__global__ void k_scan_final(const int* __restrict__ deg, int n, const int* __restrict__ bsum,
                             int* __restrict__ rowptr, int* __restrict__ cursor,
                             float* __restrict__ dinv, int E) {
    __shared__ int s[256];
    int i = blockIdx.x * 256 + threadIdx.x;
    int v = (i < n) ? deg[i] : 0;
    s[threadIdx.x] = v;
    __syncthreads();
    for (int off = 1; off < 256; off <<= 1) {
        int t = (threadIdx.x >= off) ? s[threadIdx.x - off] : 0;
        __syncthreads();
        s[threadIdx.x] += t;
        __syncthreads();
    }
    if (i < n) {
        int ex = bsum[blockIdx.x] + s[threadIdx.x] - v;  // exclusive prefix
        rowptr[i] = ex;
        cursor[i] = ex;
        dinv[i] = rsqrtf((float)(v + 1));  // +1 self-loop
        if (i == n - 1) rowptr[n] = E;
    }
}

__global__ void k_fill(const int* __restrict__ ei, int E,
                       int* __restrict__ cursor, int* __restrict__ col) {
    int i = blockIdx.x * 256 + threadIdx.x;
    if (i >= E) return;
    int s = ei[i];
    int d = ei[E + i];
    int pos = atomicAdd(cursor + d, 1);
    col[pos] = s;
}

// h1[n][k] = sum_j x[n][j] * W1[j][k]; block = 8 nodes x 32 feats
__global__ __launch_bounds__(256) void k_gemm1(const float* __restrict__ x,
                                               const float* __restrict__ W1,
                                               float* __restrict__ h1, int n) {
    __shared__ float Ws[NFEAT * HID];
    for (int i = threadIdx.x; i < NFEAT * HID; i += 256) Ws[i] = W1[i];
    __syncthreads();
    int node = blockIdx.x * 8 + (threadIdx.x >> 5);
    int k = threadIdx.x & 31;
    if (node >= n) return;
    const float4* xr = reinterpret_cast<const float4*>(x + (size_t)node * NFEAT);
    float acc = 0.f;
#pragma unroll 5
    for (int j4 = 0; j4 < NFEAT / 4; ++j4) {
        float4 v = xr[j4];
        const float* w = Ws + (j4 * 4) * HID + k;
        acc = fmaf(v.x, w[0], acc);
        acc = fmaf(v.y, w[HID], acc);
        acc = fmaf(v.z, w[2 * HID], acc);
        acc = fmaf(v.w, w[3 * HID], acc);
    }
    h1[(size_t)node * HID + k] = acc;
}

// CSR gather aggregate layer 1, fused self-loop + bias + tanh. 32 lanes/node.
__global__ __launch_bounds__(256) void k_agg1(const float* __restrict__ h1,
                                              const int* __restrict__ rowptr,
                                              const int* __restrict__ col,
                                              const float* __restrict__ dinv,
                                              const float* __restrict__ b1,
                                              float* __restrict__ h2, int n) {
    int node = blockIdx.x * 8 + (threadIdx.x >> 5);
    int k = threadIdx.x & 31;
    if (node >= n) return;
    int beg = rowptr[node], end = rowptr[node + 1];
    float acc = 0.f;
    for (int j = beg; j < end; ++j) {
        int s = col[j];
        acc = fmaf(h1[(size_t)s * HID + k], dinv[s], acc);
    }
    float dd = dinv[node];
    float val = fmaf(dd, acc, dd * dd * h1[(size_t)node * HID + k]) + b1[k];
    h2[(size_t)node * HID + k] = tanhf(val);
}

// g[n][c] = sum_k h2[n][k] * W2[k][c]
__global__ __launch_bounds__(256) void k_gemm2(const float* __restrict__ h2,
                                               const float* __restrict__ W2,
                                               float* __restrict__ g, int n) {
    __shared__ float Ws[HID * NCLS];
    for (int i = threadIdx.x; i < HID * NCLS; i += 256) Ws[i] = W2[i];
    __syncthreads();
    int t = blockIdx.x * 256 + threadIdx.x;
    if (t >= n * NCLS) return;
    int node = t / NCLS, c = t % NCLS;
    const float* hr = h2 + (size_t)node * HID;
    float acc = 0.f;
#pragma unroll
    for (int k = 0; k < HID; ++k) acc = fmaf(hr[k], Ws[k * NCLS + c], acc);
    g[t] = acc;
}

// CSR gather aggregate layer 2, fused self-loop + bias + log-softmax.
// 16 lanes/node (10 active classes), 16 nodes per 256-block.
__global__ __launch_bounds__(256) void k_agg2(const float* __restrict__ g,
                                              const int* __restrict__ rowptr,
                                              const int* __restrict__ col,
                                              const float* __restrict__ dinv,
                                              const float* __restrict__ b2,
                                              float* __restrict__ out, int n) {
    int node = blockIdx.x * 16 + (threadIdx.x >> 4);
    int c = threadIdx.x & 15;
    if (node >= n) return;
    int beg = rowptr[node], end = rowptr[node + 1];
    float acc = 0.f;
    if (c < NCLS) {
        for (int j = beg; j < end; ++j) {
            int s = col[j];
            acc = fmaf(g[(size_t)s * NCLS + c], dinv[s], acc);
        }
    }
    float dd = dinv[node];
    float val = (c < NCLS)
        ? fmaf(dd, acc, dd * dd * g[(size_t)node * NCLS + c]) + b2[c]
        : -FLT_MAX;
    float m = val;
#pragma unroll
    for (int off = 1; off < 16; off <<= 1) m = fmaxf(m, __shfl_xor(m, off, 16));
    float p = (c < NCLS) ? expf(val - m) : 0.f;
    float sum = p;
#pragma unroll
    for (int off = 1; off < 16; off <<= 1) sum += __shfl_xor(sum, off, 16);
    if (c < NCLS) out[(size_t)node * NCLS + c] = val - m - logf(sum);
}

static inline size_t align256(size_t b) { return (b + 255) & ~(size_t)255; }

extern "C" void kernel_launch(void* const* d_in, const int* in_sizes, int n_in,
                              void* d_out, int out_size, void* d_ws, size_t ws_size,
                              hipStream_t stream) {
    const float* x  = (const float*)d_in[0];
    const int*   ei = (const int*)d_in[1];   // harness delivers integers as int32
    const float* W1 = (const float*)d_in[2];
    const float* b1 = (const float*)d_in[3];
    const float* W2 = (const float*)d_in[4];
    const float* b2 = (const float*)d_in[5];
    float* out = (float*)d_out;

    const int N = in_sizes[0] / NFEAT;   // 100000
    const int E = in_sizes[1] / 2;       // 3200000

    char* p = (char*)d_ws;
    int* deg    = (int*)p;  p += align256((size_t)N * 4);
    int* rowptr = (int*)p;  p += align256((size_t)(N + 1) * 4);
    int* cursor = (int*)p;  p += align256((size_t)N * 4);
    int* bsum   = (int*)p;  p += align256(1024 * 4);
    int* col    = (int*)p;  p += align256((size_t)E * 4);
    float* dinv = (float*)p; p += align256((size_t)N * 4);
    float* h1   = (float*)p; p += align256((size_t)N * HID * 4);
    float* h2   = (float*)p; p += align256((size_t)N * HID * 4);
    float* g    = h1;  // h1 dead after k_agg1; reuse for logits

    dim3 B(256);
    int nbN = (N + 255) / 256;   // blocks over nodes (also #scan partials)
    int nbE = (E + 255) / 256;

    k_zero_i<<<nbN, B, 0, stream>>>(deg, N);
    k_hist<<<nbE, B, 0, stream>>>(ei, E, deg);
    k_scan_part<<<nbN, B, 0, stream>>>(deg, N, bsum);
    k_scan_top<<<1, 1024, 0, stream>>>(bsum, nbN);
    k_scan_final<<<nbN, B, 0, stream>>>(deg, N, bsum, rowptr, cursor, dinv, E);
    k_fill<<<nbE, B, 0, stream>>>(ei, E, cursor, col);

    k_gemm1<<<(N + 7) / 8, B, 0, stream>>>(x, W1, h1, N);
    k_agg1<<<(N + 7) / 8, B, 0, stream>>>(h1, rowptr, col, dinv, b1, h2, N);
    k_gemm2<<<(N * NCLS + 255) / 256, B, 0, stream>>>(h2, W2, g, N);
    k_agg2<<<(N + 15) / 16, B, 0, stream>>>(g, rowptr, col, dinv, b2, out, N);
}

// Round 5
// 577.431 us; speedup vs baseline: 1.5934x; 1.3971x over previous
//
#include <hip/hip_runtime.h>
#include <math.h>
#include <float.h>

#define NFEAT 300
#define HID 32
#define NCLS 10
#define BSZ 128   // nodes per dst-bucket (bucket = dst >> 7)
#define TILE 8192 // edges per k_part tile

__global__ void k_zero_i(int* __restrict__ p, int n) {
    int i = blockIdx.x * 256 + threadIdx.x;
    if (i < n) p[i] = 0;
}

__global__ void k_hist(const int* __restrict__ ei, int E, int* __restrict__ deg) {
    int i = blockIdx.x * 256 + threadIdx.x;
    if (i < E) atomicAdd(deg + ei[E + i], 1);  // dst side
}

// per-block (256-wide) partial sums of deg
__global__ void k_scan_part(const int* __restrict__ deg, int n, int* __restrict__ bsum) {
    __shared__ int s[256];
    int i = blockIdx.x * 256 + threadIdx.x;
    s[threadIdx.x] = (i < n) ? deg[i] : 0;
    __syncthreads();
    for (int off = 128; off > 0; off >>= 1) {
        if (threadIdx.x < off) s[threadIdx.x] += s[threadIdx.x + off];
        __syncthreads();
    }
    if (threadIdx.x == 0) bsum[blockIdx.x] = s[0];
}

// single-block exclusive scan of bsum[0..m), m <= 1024
__global__ void k_scan_top(int* __restrict__ bsum, int m) {
    __shared__ int s[1024];
    int tid = threadIdx.x;
    int v = (tid < m) ? bsum[tid] : 0;
    s[tid] = v;
    __syncthreads();
    for (int off = 1; off < 1024; off <<= 1) {
        int t = (tid >= off) ? s[tid - off] : 0;
        __syncthreads();
        s[tid] += t;
        __syncthreads();
    }
    if (tid < m) bsum[tid] = s[tid] - v;  // exclusive
}

// rowptr/dinv from deg + scanned block offsets
__global__ void k_scan_final(const int* __restrict__ deg, int n, const int* __restrict__ bsum,
                             int* __restrict__ rowptr, float* __restrict__ dinv, int E) {
    __shared__ int s[256];
    int i = blockIdx.x * 256 + threadIdx.x;
    int v = (i < n) ? deg[i] : 0;
    s[threadIdx.x] = v;
    __syncthreads();
    for (int off = 1; off < 256; off <<= 1) {
        int t = (threadIdx.x >= off) ? s[threadIdx.x - off] : 0;
        __syncthreads();
        s[threadIdx.x] += t;
        __syncthreads();
    }
    if (i < n) {
        int ex = bsum[blockIdx.x] + s[threadIdx.x] - v;  // exclusive prefix
        rowptr[i] = ex;
        dinv[i] = rsqrtf((float)(v + 1));  // +1 self-loop
        if (i == n - 1) rowptr[n] = E;
    }
}

__global__ void k_bcur(const int* __restrict__ rowptr, int N, int NB, int* __restrict__ bcur) {
    int b = blockIdx.x * 256 + threadIdx.x;
    if (b < NB) bcur[b] = rowptr[b << 7];
}

// partition edges into dst-buckets; output packed (dst_local<<17 | src), bucket-contiguous
__global__ __launch_bounds__(256) void k_part(const int* __restrict__ ei, int E, int NB,
                                              int* __restrict__ bcur, int* __restrict__ pp) {
    __shared__ int hist[1024], lbase[1024], gbase[1024], lcur[1024];
    __shared__ int stage[TILE], tgt[TILE];
    int* part = gbase;  // alias: gbase unused until after scan
    int tid = threadIdx.x;
    long long t0 = (long long)blockIdx.x * TILE;
    int nE = (int)(((long long)E - t0 < TILE) ? ((long long)E - t0) : TILE);

    for (int b = tid; b < NB; b += 256) hist[b] = 0;
    __syncthreads();
    for (int i = tid; i < nE; i += 256) {
        int d = ei[E + t0 + i];
        atomicAdd(&hist[d >> 7], 1);
    }
    __syncthreads();
    // exclusive scan hist -> lbase (NB <= 1024), 4 buckets per thread
    int i0 = tid * 4;
    int c0 = (i0 + 0 < NB) ? hist[i0 + 0] : 0;
    int c1 = (i0 + 1 < NB) ? hist[i0 + 1] : 0;
    int c2 = (i0 + 2 < NB) ? hist[i0 + 2] : 0;
    int c3 = (i0 + 3 < NB) ? hist[i0 + 3] : 0;
    int sum = c0 + c1 + c2 + c3;
    part[tid] = sum;
    __syncthreads();
    for (int off = 1; off < 256; off <<= 1) {
        int t = (tid >= off) ? part[tid - off] : 0;
        __syncthreads();
        part[tid] += t;
        __syncthreads();
    }
    int ex = part[tid] - sum;
    if (i0 + 0 < NB) { lbase[i0 + 0] = ex; ex += c0; }
    if (i0 + 1 < NB) { lbase[i0 + 1] = ex; ex += c1; }
    if (i0 + 2 < NB) { lbase[i0 + 2] = ex; ex += c2; }
    if (i0 + 3 < NB) { lbase[i0 + 3] = ex; ex += c3; }
    __syncthreads();  // part (=gbase) consumed; safe to overwrite
    for (int b = tid; b < NB; b += 256) {
        int h = hist[b];
        gbase[b] = h ? atomicAdd(&bcur[b], h) : 0;
        lcur[b] = 0;
    }
    __syncthreads();
    for (int i = tid; i < nE; i += 256) {
        int s = ei[t0 + i];
        int d = ei[E + t0 + i];
        int b = d >> 7;
        int lo = atomicAdd(&lcur[b], 1);
        int slot = lbase[b] + lo;
        stage[slot] = ((d - (b << 7)) << 17) | s;
        tgt[slot] = gbase[b] + lo;
    }
    __syncthreads();
    for (int i = tid; i < nE; i += 256)
        pp[tgt[i]] = stage[i];
}

// per-bucket CSR fill: col writes confined to the bucket's contiguous region
__global__ __launch_bounds__(256) void k_csr(const int* __restrict__ pp,
                                             const int* __restrict__ rowptr,
                                             int N, int* __restrict__ col) {
    __shared__ int lc[BSZ];
    __shared__ int rp[BSZ];
    int b = blockIdx.x, tid = threadIdx.x;
    int n0 = b << 7;
    int n1 = min(N, n0 + BSZ);
    if (tid < BSZ) {
        lc[tid] = 0;
        rp[tid] = (n0 + tid < N) ? rowptr[n0 + tid] : 0;
    }
    __syncthreads();
    int base = rowptr[n0];
    int cnt = rowptr[n1] - base;
    for (int i = tid; i < cnt; i += 256) {
        int v = pp[base + i];
        int s = v & 0x1FFFF;
        int dl = v >> 17;
        int lo = atomicAdd(&lc[dl], 1);
        col[rp[dl] + lo] = s;
    }
}

// h1[n][k] = sum_j x[n][j] * W1[j][k]; block = 8 nodes x 32 feats
__global__ __launch_bounds__(256) void k_gemm1(const float* __restrict__ x,
                                               const float* __restrict__ W1,
                                               float* __restrict__ h1, int n) {
    __shared__ float Ws[NFEAT * HID];
    for (int i = threadIdx.x; i < NFEAT * HID; i += 256) Ws[i] = W1[i];
    __syncthreads();
    int node = blockIdx.x * 8 + (threadIdx.x >> 5);
    int k = threadIdx.x & 31;
    if (node >= n) return;
    const float4* xr = reinterpret_cast<const float4*>(x + (size_t)node * NFEAT);
    float acc = 0.f;
#pragma unroll 5
    for (int j4 = 0; j4 < NFEAT / 4; ++j4) {
        float4 v = xr[j4];
        const float* w = Ws + (j4 * 4) * HID + k;
        acc = fmaf(v.x, w[0], acc);
        acc = fmaf(v.y, w[HID], acc);
        acc = fmaf(v.z, w[2 * HID], acc);
        acc = fmaf(v.w, w[3 * HID], acc);
    }
    h1[(size_t)node * HID + k] = acc;
}

// CSR gather aggregate layer 1, fused self-loop + bias + tanh. 32 lanes/node.
__global__ __launch_bounds__(256) void k_agg1(const float* __restrict__ h1,
                                              const int* __restrict__ rowptr,
                                              const int* __restrict__ col,
                                              const float* __restrict__ dinv,
                                              const float* __restrict__ b1,
                                              float* __restrict__ h2, int n) {
    int node = blockIdx.x * 8 + (threadIdx.x >> 5);
    int k = threadIdx.x & 31;
    if (node >= n) return;
    int beg = rowptr[node], end = rowptr[node + 1];
    float acc = 0.f;
    for (int j = beg; j < end; ++j) {
        int s = col[j];
        acc = fmaf(h1[(size_t)s * HID + k], dinv[s], acc);
    }
    float dd = dinv[node];
    float val = fmaf(dd, acc, dd * dd * h1[(size_t)node * HID + k]) + b1[k];
    h2[(size_t)node * HID + k] = tanhf(val);
}

// g[n][c] = sum_k h2[n][k] * W2[k][c]
__global__ __launch_bounds__(256) void k_gemm2(const float* __restrict__ h2,
                                               const float* __restrict__ W2,
                                               float* __restrict__ g, int n) {
    __shared__ float Ws[HID * NCLS];
    for (int i = threadIdx.x; i < HID * NCLS; i += 256) Ws[i] = W2[i];
    __syncthreads();
    int t = blockIdx.x * 256 + threadIdx.x;
    if (t >= n * NCLS) return;
    int node = t / NCLS, c = t % NCLS;
    const float* hr = h2 + (size_t)node * HID;
    float acc = 0.f;
#pragma unroll
    for (int k = 0; k < HID; ++k) acc = fmaf(hr[k], Ws[k * NCLS + c], acc);
    g[t] = acc;
}

// CSR gather aggregate layer 2, fused self-loop + bias + log-softmax.
__global__ __launch_bounds__(256) void k_agg2(const float* __restrict__ g,
                                              const int* __restrict__ rowptr,
                                              const int* __restrict__ col,
                                              const float* __restrict__ dinv,
                                              const float* __restrict__ b2,
                                              float* __restrict__ out, int n) {
    int node = blockIdx.x * 16 + (threadIdx.x >> 4);
    int c = threadIdx.x & 15;
    if (node >= n) return;
    int beg = rowptr[node], end = rowptr[node + 1];
    float acc = 0.f;
    if (c < NCLS) {
        for (int j = beg; j < end; ++j) {
            int s = col[j];
            acc = fmaf(g[(size_t)s * NCLS + c], dinv[s], acc);
        }
    }
    float dd = dinv[node];
    float val = (c < NCLS)
        ? fmaf(dd, acc, dd * dd * g[(size_t)node * NCLS + c]) + b2[c]
        : -FLT_MAX;
    float m = val;
#pragma unroll
    for (int off = 1; off < 16; off <<= 1) m = fmaxf(m, __shfl_xor(m, off, 16));
    float p = (c < NCLS) ? expf(val - m) : 0.f;
    float sum = p;
#pragma unroll
    for (int off = 1; off < 16; off <<= 1) sum += __shfl_xor(sum, off, 16);
    if (c < NCLS) out[(size_t)node * NCLS + c] = val - m - logf(sum);
}

static inline size_t align256(size_t b) { return (b + 255) & ~(size_t)255; }

extern "C" void kernel_launch(void* const* d_in, const int* in_sizes, int n_in,
                              void* d_out, int out_size, void* d_ws, size_t ws_size,
                              hipStream_t stream) {
    const float* x  = (const float*)d_in[0];
    const int*   ei = (const int*)d_in[1];
    const float* W1 = (const float*)d_in[2];
    const float* b1 = (const float*)d_in[3];
    const float* W2 = (const float*)d_in[4];
    const float* b2 = (const float*)d_in[5];
    float* out = (float*)d_out;

    const int N = in_sizes[0] / NFEAT;   // 100000
    const int E = in_sizes[1] / 2;       // 3200000
    const int NB = (N + BSZ - 1) / BSZ;  // 782 dst-buckets

    char* p = (char*)d_ws;
    int* deg    = (int*)p;  p += align256((size_t)N * 4);
    int* rowptr = (int*)p;  p += align256((size_t)(N + 1) * 4);
    int* bsum   = (int*)p;  p += align256(1024 * 4);
    int* bcur   = (int*)p;  p += align256(1024 * 4);
    int* pp     = (int*)p;  p += align256((size_t)E * 4);   // packed bucketed edges
    int* col    = (int*)p;  p += align256((size_t)E * 4);
    float* dinv = (float*)p; p += align256((size_t)N * 4);
    float* h1   = (float*)p; p += align256((size_t)N * HID * 4);
    float* h2   = (float*)p; p += align256((size_t)N * HID * 4);
    float* g    = h1;  // h1 dead after k_agg1; reuse for logits

    dim3 B(256);
    int nbN = (N + 255) / 256;
    int nbE = (E + 255) / 256;
    int nT  = (E + TILE - 1) / TILE;

    k_zero_i<<<nbN, B, 0, stream>>>(deg, N);
    k_hist<<<nbE, B, 0, stream>>>(ei, E, deg);
    k_scan_part<<<nbN, B, 0, stream>>>(deg, N, bsum);
    k_scan_top<<<1, 1024, 0, stream>>>(bsum, nbN);
    k_scan_final<<<nbN, B, 0, stream>>>(deg, N, bsum, rowptr, dinv, E);
    k_bcur<<<(NB + 255) / 256, B, 0, stream>>>(rowptr, N, NB, bcur);
    k_part<<<nT, B, 0, stream>>>(ei, E, NB, bcur, pp);
    k_csr<<<NB, B, 0, stream>>>(pp, rowptr, N, col);

    k_gemm1<<<(N + 7) / 8, B, 0, stream>>>(x, W1, h1, N);
    k_agg1<<<(N + 7) / 8, B, 0, stream>>>(h1, rowptr, col, dinv, b1, h2, N);
    k_gemm2<<<(N * NCLS + 255) / 256, B, 0, stream>>>(h2, W2, g, N);
    k_agg2<<<(N + 15) / 16, B, 0, stream>>>(g, rowptr, col, dinv, b2, out, N);
}

// Round 6
// 509.284 us; speedup vs baseline: 1.8066x; 1.1338x over previous
//
#include <hip/hip_runtime.h>
#include <math.h>
#include <float.h>

#define NFEAT 300
#define HID 32
#define NCLS 10
#define BSZ 128   // nodes per dst-bucket (bucket = dst >> 7)
#define TILE 8192 // edges per k_part tile
#define KC 30     // feature chunk for gemm1 LDS transpose

__global__ void k_zero_i(int* __restrict__ p, int n) {
    int i = blockIdx.x * 256 + threadIdx.x;
    if (i < n) p[i] = 0;
}

__global__ void k_hist(const int* __restrict__ ei, int E, int* __restrict__ deg) {
    int i = blockIdx.x * 256 + threadIdx.x;
    if (i < E) atomicAdd(deg + ei[E + i], 1);  // dst side
}

// per-block (256-wide) partial sums of deg
__global__ void k_scan_part(const int* __restrict__ deg, int n, int* __restrict__ bsum) {
    __shared__ int s[256];
    int i = blockIdx.x * 256 + threadIdx.x;
    s[threadIdx.x] = (i < n) ? deg[i] : 0;
    __syncthreads();
    for (int off = 128; off > 0; off >>= 1) {
        if (threadIdx.x < off) s[threadIdx.x] += s[threadIdx.x + off];
        __syncthreads();
    }
    if (threadIdx.x == 0) bsum[blockIdx.x] = s[0];
}

// single-block exclusive scan of bsum[0..m), m <= 1024
__global__ void k_scan_top(int* __restrict__ bsum, int m) {
    __shared__ int s[1024];
    int tid = threadIdx.x;
    int v = (tid < m) ? bsum[tid] : 0;
    s[tid] = v;
    __syncthreads();
    for (int off = 1; off < 1024; off <<= 1) {
        int t = (tid >= off) ? s[tid - off] : 0;
        __syncthreads();
        s[tid] += t;
        __syncthreads();
    }
    if (tid < m) bsum[tid] = s[tid] - v;  // exclusive
}

// rowptr/dinv from deg + scanned block offsets
__global__ void k_scan_final(const int* __restrict__ deg, int n, const int* __restrict__ bsum,
                             int* __restrict__ rowptr, float* __restrict__ dinv, int E) {
    __shared__ int s[256];
    int i = blockIdx.x * 256 + threadIdx.x;
    int v = (i < n) ? deg[i] : 0;
    s[threadIdx.x] = v;
    __syncthreads();
    for (int off = 1; off < 256; off <<= 1) {
        int t = (threadIdx.x >= off) ? s[threadIdx.x - off] : 0;
        __syncthreads();
        s[threadIdx.x] += t;
        __syncthreads();
    }
    if (i < n) {
        int ex = bsum[blockIdx.x] + s[threadIdx.x] - v;  // exclusive prefix
        rowptr[i] = ex;
        dinv[i] = rsqrtf((float)(v + 1));  // +1 self-loop
        if (i == n - 1) rowptr[n] = E;
    }
}

__global__ void k_bcur(const int* __restrict__ rowptr, int N, int NB, int* __restrict__ bcur) {
    int b = blockIdx.x * 256 + threadIdx.x;
    if (b < NB) bcur[b] = rowptr[b << 7];
}

// partition edges into dst-buckets; output packed (dst_local<<17 | src), bucket-contiguous
__global__ __launch_bounds__(256) void k_part(const int* __restrict__ ei, int E, int NB,
                                              int* __restrict__ bcur, int* __restrict__ pp) {
    __shared__ int hist[1024], lbase[1024], gbase[1024], lcur[1024];
    __shared__ int stage[TILE], tgt[TILE];
    int* part = gbase;  // alias: gbase unused until after scan
    int tid = threadIdx.x;
    long long t0 = (long long)blockIdx.x * TILE;
    int nE = (int)(((long long)E - t0 < TILE) ? ((long long)E - t0) : TILE);

    for (int b = tid; b < NB; b += 256) hist[b] = 0;
    __syncthreads();
    for (int i = tid; i < nE; i += 256) {
        int d = ei[E + t0 + i];
        atomicAdd(&hist[d >> 7], 1);
    }
    __syncthreads();
    // exclusive scan hist -> lbase (NB <= 1024), 4 buckets per thread
    int i0 = tid * 4;
    int c0 = (i0 + 0 < NB) ? hist[i0 + 0] : 0;
    int c1 = (i0 + 1 < NB) ? hist[i0 + 1] : 0;
    int c2 = (i0 + 2 < NB) ? hist[i0 + 2] : 0;
    int c3 = (i0 + 3 < NB) ? hist[i0 + 3] : 0;
    int sum = c0 + c1 + c2 + c3;
    part[tid] = sum;
    __syncthreads();
    for (int off = 1; off < 256; off <<= 1) {
        int t = (tid >= off) ? part[tid - off] : 0;
        __syncthreads();
        part[tid] += t;
        __syncthreads();
    }
    int ex = part[tid] - sum;
    if (i0 + 0 < NB) { lbase[i0 + 0] = ex; ex += c0; }
    if (i0 + 1 < NB) { lbase[i0 + 1] = ex; ex += c1; }
    if (i0 + 2 < NB) { lbase[i0 + 2] = ex; ex += c2; }
    if (i0 + 3 < NB) { lbase[i0 + 3] = ex; ex += c3; }
    __syncthreads();  // part (=gbase) consumed; safe to overwrite
    for (int b = tid; b < NB; b += 256) {
        int h = hist[b];
        gbase[b] = h ? atomicAdd(&bcur[b], h) : 0;
        lcur[b] = 0;
    }
    __syncthreads();
    for (int i = tid; i < nE; i += 256) {
        int s = ei[t0 + i];
        int d = ei[E + t0 + i];
        int b = d >> 7;
        int lo = atomicAdd(&lcur[b], 1);
        int slot = lbase[b] + lo;
        stage[slot] = ((d - (b << 7)) << 17) | s;
        tgt[slot] = gbase[b] + lo;
    }
    __syncthreads();
    for (int i = tid; i < nE; i += 256)
        pp[tgt[i]] = stage[i];
}

// per-bucket CSR fill: col writes confined to the bucket's contiguous region
__global__ __launch_bounds__(256) void k_csr(const int* __restrict__ pp,
                                             const int* __restrict__ rowptr,
                                             int N, int* __restrict__ col) {
    __shared__ int lc[BSZ];
    __shared__ int rp[BSZ];
    int b = blockIdx.x, tid = threadIdx.x;
    int n0 = b << 7;
    int n1 = min(N, n0 + BSZ);
    if (tid < BSZ) {
        lc[tid] = 0;
        rp[tid] = (n0 + tid < N) ? rowptr[n0 + tid] : 0;
    }
    __syncthreads();
    int base = rowptr[n0];
    int cnt = rowptr[n1] - base;
    for (int i = tid; i < cnt; i += 256) {
        int v = pp[base + i];
        int s = v & 0x1FFFF;
        int dl = v >> 17;
        int lo = atomicAdd(&lc[dl], 1);
        col[rp[dl] + lo] = s;
    }
}

// h1[n][k] = sum_j x[n][j] * W1[j][k]
// lane = node; x via LDS transpose (stride-1 b32 reads); W row wave-uniform -> SGPR
__global__ __launch_bounds__(256) void k_gemm1(const float* __restrict__ x,
                                               const float* __restrict__ W1,
                                               float* __restrict__ h1, int n) {
    __shared__ float xT[KC][256];
    int tid = threadIdx.x;
    int node = blockIdx.x * 256 + tid;
    bool valid = node < n;
    const float* xr = x + (size_t)(valid ? node : (n - 1)) * NFEAT;
    float acc[HID];
#pragma unroll
    for (int k = 0; k < HID; ++k) acc[k] = 0.f;

    for (int c = 0; c < NFEAT / KC; ++c) {
        __syncthreads();  // protect previous chunk's reads
        const float2* src = reinterpret_cast<const float2*>(xr + c * KC);
#pragma unroll
        for (int i = 0; i < KC / 2; ++i) {
            float2 v = src[i];
            xT[2 * i][tid] = v.x;
            xT[2 * i + 1][tid] = v.y;
        }
        __syncthreads();
        const float* wbase = W1 + (size_t)c * KC * HID;
#pragma unroll 5
        for (int j = 0; j < KC; ++j) {
            float xv = xT[j][tid];
            const float4* wr = reinterpret_cast<const float4*>(wbase + (size_t)j * HID);
#pragma unroll
            for (int q = 0; q < HID / 4; ++q) {
                float4 wv = wr[q];  // wave-uniform -> s_load
                acc[4 * q + 0] = fmaf(xv, wv.x, acc[4 * q + 0]);
                acc[4 * q + 1] = fmaf(xv, wv.y, acc[4 * q + 1]);
                acc[4 * q + 2] = fmaf(xv, wv.z, acc[4 * q + 2]);
                acc[4 * q + 3] = fmaf(xv, wv.w, acc[4 * q + 3]);
            }
        }
    }
    if (valid) {
        float4* dst = reinterpret_cast<float4*>(h1 + (size_t)node * HID);
#pragma unroll
        for (int q = 0; q < HID / 4; ++q)
            dst[q] = make_float4(acc[4 * q], acc[4 * q + 1], acc[4 * q + 2], acc[4 * q + 3]);
    }
}

// CSR gather aggregate layer 1, fused self-loop + bias + tanh. 32 lanes/node.
__global__ __launch_bounds__(256) void k_agg1(const float* __restrict__ h1,
                                              const int* __restrict__ rowptr,
                                              const int* __restrict__ col,
                                              const float* __restrict__ dinv,
                                              const float* __restrict__ b1,
                                              float* __restrict__ h2, int n) {
    int node = blockIdx.x * 8 + (threadIdx.x >> 5);
    int k = threadIdx.x & 31;
    if (node >= n) return;
    int beg = rowptr[node], end = rowptr[node + 1];
    float acc = 0.f;
    for (int j = beg; j < end; ++j) {
        int s = col[j];
        acc = fmaf(h1[(size_t)s * HID + k], dinv[s], acc);
    }
    float dd = dinv[node];
    float val = fmaf(dd, acc, dd * dd * h1[(size_t)node * HID + k]) + b1[k];
    h2[(size_t)node * HID + k] = tanhf(val);
}

// g[n][c] = sum_k h2[n][k] * W2[k][c]
__global__ __launch_bounds__(256) void k_gemm2(const float* __restrict__ h2,
                                               const float* __restrict__ W2,
                                               float* __restrict__ g, int n) {
    __shared__ float Ws[HID * NCLS];
    for (int i = threadIdx.x; i < HID * NCLS; i += 256) Ws[i] = W2[i];
    __syncthreads();
    int t = blockIdx.x * 256 + threadIdx.x;
    if (t >= n * NCLS) return;
    int node = t / NCLS, c = t % NCLS;
    const float* hr = h2 + (size_t)node * HID;
    float acc = 0.f;
#pragma unroll
    for (int k = 0; k < HID; ++k) acc = fmaf(hr[k], Ws[k * NCLS + c], acc);
    g[t] = acc;
}

// CSR gather aggregate layer 2, fused self-loop + bias + log-softmax.
__global__ __launch_bounds__(256) void k_agg2(const float* __restrict__ g,
                                              const int* __restrict__ rowptr,
                                              const int* __restrict__ col,
                                              const float* __restrict__ dinv,
                                              const float* __restrict__ b2,
                                              float* __restrict__ out, int n) {
    int node = blockIdx.x * 16 + (threadIdx.x >> 4);
    int c = threadIdx.x & 15;
    if (node >= n) return;
    int beg = rowptr[node], end = rowptr[node + 1];
    float acc = 0.f;
    if (c < NCLS) {
        for (int j = beg; j < end; ++j) {
            int s = col[j];
            acc = fmaf(g[(size_t)s * NCLS + c], dinv[s], acc);
        }
    }
    float dd = dinv[node];
    float val = (c < NCLS)
        ? fmaf(dd, acc, dd * dd * g[(size_t)node * NCLS + c]) + b2[c]
        : -FLT_MAX;
    float m = val;
#pragma unroll
    for (int off = 1; off < 16; off <<= 1) m = fmaxf(m, __shfl_xor(m, off, 16));
    float p = (c < NCLS) ? expf(val - m) : 0.f;
    float sum = p;
#pragma unroll
    for (int off = 1; off < 16; off <<= 1) sum += __shfl_xor(sum, off, 16);
    if (c < NCLS) out[(size_t)node * NCLS + c] = val - m - logf(sum);
}

static inline size_t align256(size_t b) { return (b + 255) & ~(size_t)255; }

extern "C" void kernel_launch(void* const* d_in, const int* in_sizes, int n_in,
                              void* d_out, int out_size, void* d_ws, size_t ws_size,
                              hipStream_t stream) {
    const float* x  = (const float*)d_in[0];
    const int*   ei = (const int*)d_in[1];
    const float* W1 = (const float*)d_in[2];
    const float* b1 = (const float*)d_in[3];
    const float* W2 = (const float*)d_in[4];
    const float* b2 = (const float*)d_in[5];
    float* out = (float*)d_out;

    const int N = in_sizes[0] / NFEAT;   // 100000
    const int E = in_sizes[1] / 2;       // 3200000
    const int NB = (N + BSZ - 1) / BSZ;  // 782 dst-buckets

    char* p = (char*)d_ws;
    int* deg    = (int*)p;  p += align256((size_t)N * 4);
    int* rowptr = (int*)p;  p += align256((size_t)(N + 1) * 4);
    int* bsum   = (int*)p;  p += align256(1024 * 4);
    int* bcur   = (int*)p;  p += align256(1024 * 4);
    int* pp     = (int*)p;  p += align256((size_t)E * 4);   // packed bucketed edges
    int* col    = (int*)p;  p += align256((size_t)E * 4);
    float* dinv = (float*)p; p += align256((size_t)N * 4);
    float* h1   = (float*)p; p += align256((size_t)N * HID * 4);
    float* h2   = (float*)p; p += align256((size_t)N * HID * 4);
    float* g    = h1;  // h1 dead after k_agg1; reuse for logits

    dim3 B(256);
    int nbN = (N + 255) / 256;
    int nbE = (E + 255) / 256;
    int nT  = (E + TILE - 1) / TILE;

    k_zero_i<<<nbN, B, 0, stream>>>(deg, N);
    k_hist<<<nbE, B, 0, stream>>>(ei, E, deg);
    k_scan_part<<<nbN, B, 0, stream>>>(deg, N, bsum);
    k_scan_top<<<1, 1024, 0, stream>>>(bsum, nbN);
    k_scan_final<<<nbN, B, 0, stream>>>(deg, N, bsum, rowptr, dinv, E);
    k_bcur<<<(NB + 255) / 256, B, 0, stream>>>(rowptr, N, NB, bcur);
    k_part<<<nT, B, 0, stream>>>(ei, E, NB, bcur, pp);
    k_csr<<<NB, B, 0, stream>>>(pp, rowptr, N, col);

    k_gemm1<<<nbN, B, 0, stream>>>(x, W1, h1, N);
    k_agg1<<<(N + 7) / 8, B, 0, stream>>>(h1, rowptr, col, dinv, b1, h2, N);
    k_gemm2<<<(N * NCLS + 255) / 256, B, 0, stream>>>(h2, W2, g, N);
    k_agg2<<<(N + 15) / 16, B, 0, stream>>>(g, rowptr, col, dinv, b2, out, N);
}

// Round 7
// 415.681 us; speedup vs baseline: 2.2134x; 1.2252x over previous
//
#include <hip/hip_runtime.h>
#include <math.h>
#include <float.h>

#define NFEAT 300
#define HID 32
#define NCLS 10
#define GP 16     // padded row stride for layer-2 logits
#define BSZ 128   // nodes per dst-bucket (bucket = dst >> 7)
#define TILE 8192 // edges per k_part tile
#define KC 30     // feature chunk for gemm1 LDS transpose

__global__ void k_zero_i(int* __restrict__ p, int n) {
    int i = blockIdx.x * 256 + threadIdx.x;
    if (i < n) p[i] = 0;
}

__global__ void k_hist(const int* __restrict__ ei, int E, int* __restrict__ deg) {
    int i = blockIdx.x * 256 + threadIdx.x;
    if (i < E) atomicAdd(deg + ei[E + i], 1);  // dst side
}

// per-block (256-wide) partial sums of deg
__global__ void k_scan_part(const int* __restrict__ deg, int n, int* __restrict__ bsum) {
    __shared__ int s[256];
    int i = blockIdx.x * 256 + threadIdx.x;
    s[threadIdx.x] = (i < n) ? deg[i] : 0;
    __syncthreads();
    for (int off = 128; off > 0; off >>= 1) {
        if (threadIdx.x < off) s[threadIdx.x] += s[threadIdx.x + off];
        __syncthreads();
    }
    if (threadIdx.x == 0) bsum[blockIdx.x] = s[0];
}

// single-block exclusive scan of bsum[0..m), m <= 1024
__global__ void k_scan_top(int* __restrict__ bsum, int m) {
    __shared__ int s[1024];
    int tid = threadIdx.x;
    int v = (tid < m) ? bsum[tid] : 0;
    s[tid] = v;
    __syncthreads();
    for (int off = 1; off < 1024; off <<= 1) {
        int t = (tid >= off) ? s[tid - off] : 0;
        __syncthreads();
        s[tid] += t;
        __syncthreads();
    }
    if (tid < m) bsum[tid] = s[tid] - v;  // exclusive
}

// rowptr/dinv from deg + scanned block offsets
__global__ void k_scan_final(const int* __restrict__ deg, int n, const int* __restrict__ bsum,
                             int* __restrict__ rowptr, float* __restrict__ dinv, int E) {
    __shared__ int s[256];
    int i = blockIdx.x * 256 + threadIdx.x;
    int v = (i < n) ? deg[i] : 0;
    s[threadIdx.x] = v;
    __syncthreads();
    for (int off = 1; off < 256; off <<= 1) {
        int t = (threadIdx.x >= off) ? s[threadIdx.x - off] : 0;
        __syncthreads();
        s[threadIdx.x] += t;
        __syncthreads();
    }
    if (i < n) {
        int ex = bsum[blockIdx.x] + s[threadIdx.x] - v;  // exclusive prefix
        rowptr[i] = ex;
        dinv[i] = rsqrtf((float)(v + 1));  // +1 self-loop
        if (i == n - 1) rowptr[n] = E;
    }
}

__global__ void k_bcur(const int* __restrict__ rowptr, int N, int NB, int* __restrict__ bcur) {
    int b = blockIdx.x * 256 + threadIdx.x;
    if (b < NB) bcur[b] = rowptr[b << 7];
}

// partition edges into dst-buckets; output packed (dst_local<<17 | src), bucket-contiguous
__global__ __launch_bounds__(256) void k_part(const int* __restrict__ ei, int E, int NB,
                                              int* __restrict__ bcur, int* __restrict__ pp) {
    __shared__ int hist[1024], lbase[1024], gbase[1024], lcur[1024];
    __shared__ int stage[TILE], tgt[TILE];
    int* part = gbase;  // alias: gbase unused until after scan
    int tid = threadIdx.x;
    long long t0 = (long long)blockIdx.x * TILE;
    int nE = (int)(((long long)E - t0 < TILE) ? ((long long)E - t0) : TILE);

    for (int b = tid; b < NB; b += 256) hist[b] = 0;
    __syncthreads();
    for (int i = tid; i < nE; i += 256) {
        int d = ei[E + t0 + i];
        atomicAdd(&hist[d >> 7], 1);
    }
    __syncthreads();
    // exclusive scan hist -> lbase (NB <= 1024), 4 buckets per thread
    int i0 = tid * 4;
    int c0 = (i0 + 0 < NB) ? hist[i0 + 0] : 0;
    int c1 = (i0 + 1 < NB) ? hist[i0 + 1] : 0;
    int c2 = (i0 + 2 < NB) ? hist[i0 + 2] : 0;
    int c3 = (i0 + 3 < NB) ? hist[i0 + 3] : 0;
    int sum = c0 + c1 + c2 + c3;
    part[tid] = sum;
    __syncthreads();
    for (int off = 1; off < 256; off <<= 1) {
        int t = (tid >= off) ? part[tid - off] : 0;
        __syncthreads();
        part[tid] += t;
        __syncthreads();
    }
    int ex = part[tid] - sum;
    if (i0 + 0 < NB) { lbase[i0 + 0] = ex; ex += c0; }
    if (i0 + 1 < NB) { lbase[i0 + 1] = ex; ex += c1; }
    if (i0 + 2 < NB) { lbase[i0 + 2] = ex; ex += c2; }
    if (i0 + 3 < NB) { lbase[i0 + 3] = ex; ex += c3; }
    __syncthreads();  // part (=gbase) consumed; safe to overwrite
    for (int b = tid; b < NB; b += 256) {
        int h = hist[b];
        gbase[b] = h ? atomicAdd(&bcur[b], h) : 0;
        lcur[b] = 0;
    }
    __syncthreads();
    for (int i = tid; i < nE; i += 256) {
        int s = ei[t0 + i];
        int d = ei[E + t0 + i];
        int b = d >> 7;
        int lo = atomicAdd(&lcur[b], 1);
        int slot = lbase[b] + lo;
        stage[slot] = ((d - (b << 7)) << 17) | s;
        tgt[slot] = gbase[b] + lo;
    }
    __syncthreads();
    for (int i = tid; i < nE; i += 256)
        pp[tgt[i]] = stage[i];
}

// per-bucket CSR fill: col writes confined to the bucket's contiguous region
__global__ __launch_bounds__(256) void k_csr(const int* __restrict__ pp,
                                             const int* __restrict__ rowptr,
                                             int N, int* __restrict__ col) {
    __shared__ int lc[BSZ];
    __shared__ int rp[BSZ];
    int b = blockIdx.x, tid = threadIdx.x;
    int n0 = b << 7;
    int n1 = min(N, n0 + BSZ);
    if (tid < BSZ) {
        lc[tid] = 0;
        rp[tid] = (n0 + tid < N) ? rowptr[n0 + tid] : 0;
    }
    __syncthreads();
    int base = rowptr[n0];
    int cnt = rowptr[n1] - base;
    for (int i = tid; i < cnt; i += 256) {
        int v = pp[base + i];
        int s = v & 0x1FFFF;
        int dl = v >> 17;
        int lo = atomicAdd(&lc[dl], 1);
        col[rp[dl] + lo] = s;
    }
}

// h1s[n][k] = dinv[n] * sum_j x[n][j] * W1[j][k]   (pre-scaled by dinv!)
// lane = node; x via LDS transpose (stride-1 b32 reads); W row wave-uniform -> SGPR
__global__ __launch_bounds__(256) void k_gemm1(const float* __restrict__ x,
                                               const float* __restrict__ W1,
                                               const float* __restrict__ dinv,
                                               float* __restrict__ h1s, int n) {
    __shared__ float xT[KC][256];
    int tid = threadIdx.x;
    int node = blockIdx.x * 256 + tid;
    bool valid = node < n;
    const float* xr = x + (size_t)(valid ? node : (n - 1)) * NFEAT;
    float acc[HID];
#pragma unroll
    for (int k = 0; k < HID; ++k) acc[k] = 0.f;

    for (int c = 0; c < NFEAT / KC; ++c) {
        __syncthreads();  // protect previous chunk's reads
        const float2* src = reinterpret_cast<const float2*>(xr + c * KC);
#pragma unroll
        for (int i = 0; i < KC / 2; ++i) {
            float2 v = src[i];
            xT[2 * i][tid] = v.x;
            xT[2 * i + 1][tid] = v.y;
        }
        __syncthreads();
        const float* wbase = W1 + (size_t)c * KC * HID;
#pragma unroll 5
        for (int j = 0; j < KC; ++j) {
            float xv = xT[j][tid];
            const float4* wr = reinterpret_cast<const float4*>(wbase + (size_t)j * HID);
#pragma unroll
            for (int q = 0; q < HID / 4; ++q) {
                float4 wv = wr[q];  // wave-uniform -> s_load
                acc[4 * q + 0] = fmaf(xv, wv.x, acc[4 * q + 0]);
                acc[4 * q + 1] = fmaf(xv, wv.y, acc[4 * q + 1]);
                acc[4 * q + 2] = fmaf(xv, wv.z, acc[4 * q + 2]);
                acc[4 * q + 3] = fmaf(xv, wv.w, acc[4 * q + 3]);
            }
        }
    }
    if (valid) {
        float dd = dinv[node];
        float4* dst = reinterpret_cast<float4*>(h1s + (size_t)node * HID);
#pragma unroll
        for (int q = 0; q < HID / 4; ++q)
            dst[q] = make_float4(dd * acc[4 * q], dd * acc[4 * q + 1],
                                 dd * acc[4 * q + 2], dd * acc[4 * q + 3]);
    }
}

// CSR gather aggregate layer 1 (pre-scaled h1s), fused bias + tanh.
// 8 lanes/node x float4; 2-edge unroll for MLP. 32 nodes per 256-block.
__global__ __launch_bounds__(256) void k_agg1(const float* __restrict__ h1s,
                                              const int* __restrict__ rowptr,
                                              const int* __restrict__ col,
                                              const float* __restrict__ dinv,
                                              const float* __restrict__ b1,
                                              float* __restrict__ h2, int n) {
    int node = blockIdx.x * 32 + (threadIdx.x >> 3);
    int l = threadIdx.x & 7;  // float4 lane within node
    if (node >= n) return;
    const float4* h4 = reinterpret_cast<const float4*>(h1s);
    int beg = rowptr[node], end = rowptr[node + 1];
    float4 a0 = h4[(size_t)node * 8 + l];  // self-loop term (pre-scaled)
    float4 a1 = make_float4(0.f, 0.f, 0.f, 0.f);
    int j = beg;
    for (; j + 1 < end; j += 2) {
        int s0 = col[j], s1 = col[j + 1];
        float4 v0 = h4[(size_t)s0 * 8 + l];
        float4 v1 = h4[(size_t)s1 * 8 + l];
        a0.x += v0.x; a0.y += v0.y; a0.z += v0.z; a0.w += v0.w;
        a1.x += v1.x; a1.y += v1.y; a1.z += v1.z; a1.w += v1.w;
    }
    if (j < end) {
        float4 v = h4[(size_t)col[j] * 8 + l];
        a0.x += v.x; a0.y += v.y; a0.z += v.z; a0.w += v.w;
    }
    float dd = dinv[node];
    const float4* b4 = reinterpret_cast<const float4*>(b1);
    float4 bv = b4[l];
    float4 r;
    r.x = tanhf(fmaf(dd, a0.x + a1.x, bv.x));
    r.y = tanhf(fmaf(dd, a0.y + a1.y, bv.y));
    r.z = tanhf(fmaf(dd, a0.z + a1.z, bv.z));
    r.w = tanhf(fmaf(dd, a0.w + a1.w, bv.w));
    reinterpret_cast<float4*>(h2)[(size_t)node * 8 + l] = r;
}

// gs[n][c] = dinv[n] * sum_k h2[n][k] * W2[k][c], padded row stride GP=16
__global__ __launch_bounds__(256) void k_gemm2(const float* __restrict__ h2,
                                               const float* __restrict__ W2,
                                               const float* __restrict__ dinv,
                                               float* __restrict__ gs, int n) {
    __shared__ float Ws[HID * NCLS];
    for (int i = threadIdx.x; i < HID * NCLS; i += 256) Ws[i] = W2[i];
    __syncthreads();
    int t = blockIdx.x * 256 + threadIdx.x;
    int node = t >> 4, c = t & 15;
    if (node >= n || c >= NCLS) return;
    const float* hr = h2 + (size_t)node * HID;
    float acc = 0.f;
#pragma unroll
    for (int k = 0; k < HID; ++k) acc = fmaf(hr[k], Ws[k * NCLS + c], acc);
    gs[(size_t)node * GP + c] = acc * dinv[node];
}

// CSR gather aggregate layer 2 (pre-scaled gs, 64B-aligned rows),
// fused bias + log-softmax. 16 lanes/node.
__global__ __launch_bounds__(256) void k_agg2(const float* __restrict__ gs,
                                              const int* __restrict__ rowptr,
                                              const int* __restrict__ col,
                                              const float* __restrict__ dinv,
                                              const float* __restrict__ b2,
                                              float* __restrict__ out, int n) {
    int node = blockIdx.x * 16 + (threadIdx.x >> 4);
    int c = threadIdx.x & 15;
    if (node >= n) return;
    int beg = rowptr[node], end = rowptr[node + 1];
    float acc = 0.f;
    if (c < NCLS) {
        acc = gs[(size_t)node * GP + c];  // self-loop term
        for (int j = beg; j < end; ++j)
            acc += gs[(size_t)col[j] * GP + c];
    }
    float dd = dinv[node];
    float val = (c < NCLS) ? fmaf(dd, acc, b2[c]) : -FLT_MAX;
    float m = val;
#pragma unroll
    for (int off = 1; off < 16; off <<= 1) m = fmaxf(m, __shfl_xor(m, off, 16));
    float p = (c < NCLS) ? expf(val - m) : 0.f;
    float sum = p;
#pragma unroll
    for (int off = 1; off < 16; off <<= 1) sum += __shfl_xor(sum, off, 16);
    if (c < NCLS) out[(size_t)node * NCLS + c] = val - m - logf(sum);
}

static inline size_t align256(size_t b) { return (b + 255) & ~(size_t)255; }

extern "C" void kernel_launch(void* const* d_in, const int* in_sizes, int n_in,
                              void* d_out, int out_size, void* d_ws, size_t ws_size,
                              hipStream_t stream) {
    const float* x  = (const float*)d_in[0];
    const int*   ei = (const int*)d_in[1];
    const float* W1 = (const float*)d_in[2];
    const float* b1 = (const float*)d_in[3];
    const float* W2 = (const float*)d_in[4];
    const float* b2 = (const float*)d_in[5];
    float* out = (float*)d_out;

    const int N = in_sizes[0] / NFEAT;   // 100000
    const int E = in_sizes[1] / 2;       // 3200000
    const int NB = (N + BSZ - 1) / BSZ;  // 782 dst-buckets

    char* p = (char*)d_ws;
    int* deg    = (int*)p;  p += align256((size_t)N * 4);
    int* rowptr = (int*)p;  p += align256((size_t)(N + 1) * 4);
    int* bsum   = (int*)p;  p += align256(1024 * 4);
    int* bcur   = (int*)p;  p += align256(1024 * 4);
    int* pp     = (int*)p;  p += align256((size_t)E * 4);   // packed bucketed edges
    int* col    = (int*)p;  p += align256((size_t)E * 4);
    float* dinv = (float*)p; p += align256((size_t)N * 4);
    float* h1s  = (float*)p; p += align256((size_t)N * HID * 4);
    float* h2   = (float*)p; p += align256((size_t)N * HID * 4);
    float* gs   = h1s;  // N*GP floats; h1s dead after k_agg1

    dim3 B(256);
    int nbN = (N + 255) / 256;
    int nbE = (E + 255) / 256;
    int nT  = (E + TILE - 1) / TILE;

    k_zero_i<<<nbN, B, 0, stream>>>(deg, N);
    k_hist<<<nbE, B, 0, stream>>>(ei, E, deg);
    k_scan_part<<<nbN, B, 0, stream>>>(deg, N, bsum);
    k_scan_top<<<1, 1024, 0, stream>>>(bsum, nbN);
    k_scan_final<<<nbN, B, 0, stream>>>(deg, N, bsum, rowptr, dinv, E);
    k_bcur<<<(NB + 255) / 256, B, 0, stream>>>(rowptr, N, NB, bcur);
    k_part<<<nT, B, 0, stream>>>(ei, E, NB, bcur, pp);
    k_csr<<<NB, B, 0, stream>>>(pp, rowptr, N, col);

    k_gemm1<<<nbN, B, 0, stream>>>(x, W1, dinv, h1s, N);
    k_agg1<<<(N + 31) / 32, B, 0, stream>>>(h1s, rowptr, col, dinv, b1, h2, N);
    k_gemm2<<<(N * 16 + 255) / 256, B, 0, stream>>>(h2, W2, dinv, gs, N);
    k_agg2<<<(N + 15) / 16, B, 0, stream>>>(gs, rowptr, col, dinv, b2, out, N);
}

// Round 8
// 311.515 us; speedup vs baseline: 2.9535x; 1.3344x over previous
//
#include <hip/hip_runtime.h>
#include <math.h>
#include <float.h>

#define NFEAT 300
#define HID 32
#define NCLS 10
#define GP 16     // padded row stride for layer-2 logits
#define BSZ 128   // nodes per dst-bucket (bucket = dst >> 7)
#define TILE 8192 // edges per k_part tile
#define KC 30     // feature chunk for gemm1 LDS transpose

__global__ void k_zero_i(int* __restrict__ p, int n) {
    int i = blockIdx.x * 256 + threadIdx.x;
    if (i < n) p[i] = 0;
}

// bucket-level histogram: LDS-privatized, merged via global atomics (782 counters)
__global__ __launch_bounds__(256) void k_bhist(const int* __restrict__ ei, int E, int NB,
                                               int* __restrict__ bcnt) {
    __shared__ int h[1024];
    for (int i = threadIdx.x; i < NB; i += 256) h[i] = 0;
    __syncthreads();
    for (long long i = (long long)blockIdx.x * 256 + threadIdx.x; i < E;
         i += (long long)gridDim.x * 256)
        atomicAdd(&h[ei[E + i] >> 7], 1);
    __syncthreads();
    for (int i = threadIdx.x; i < NB; i += 256) {
        int v = h[i];
        if (v) atomicAdd(&bcnt[i], v);
    }
}

// single-block exclusive scan of bucket counts -> bases (and bcur seed)
__global__ void k_bscan(const int* __restrict__ bcnt, int NB, int E,
                        int* __restrict__ bases, int* __restrict__ bcur) {
    __shared__ int s[1024];
    int tid = threadIdx.x;
    int v = (tid < NB) ? bcnt[tid] : 0;
    s[tid] = v;
    __syncthreads();
    for (int off = 1; off < 1024; off <<= 1) {
        int t = (tid >= off) ? s[tid - off] : 0;
        __syncthreads();
        s[tid] += t;
        __syncthreads();
    }
    if (tid < NB) {
        int ex = s[tid] - v;
        bases[tid] = ex;
        bcur[tid] = ex;
        if (tid == NB - 1) bases[NB] = E;
    }
}

// partition edges into dst-buckets; output packed (dst_local<<17 | src), bucket-contiguous
__global__ __launch_bounds__(256) void k_part(const int* __restrict__ ei, int E, int NB,
                                              int* __restrict__ bcur, int* __restrict__ pp) {
    __shared__ int hist[1024], lbase[1024], gbase[1024], lcur[1024];
    __shared__ int stage[TILE], tgt[TILE];
    int* part = gbase;  // alias: gbase unused until after scan
    int tid = threadIdx.x;
    long long t0 = (long long)blockIdx.x * TILE;
    int nE = (int)(((long long)E - t0 < TILE) ? ((long long)E - t0) : TILE);

    for (int b = tid; b < NB; b += 256) hist[b] = 0;
    __syncthreads();
    for (int i = tid; i < nE; i += 256) {
        int d = ei[E + t0 + i];
        atomicAdd(&hist[d >> 7], 1);
    }
    __syncthreads();
    // exclusive scan hist -> lbase (NB <= 1024), 4 buckets per thread
    int i0 = tid * 4;
    int c0 = (i0 + 0 < NB) ? hist[i0 + 0] : 0;
    int c1 = (i0 + 1 < NB) ? hist[i0 + 1] : 0;
    int c2 = (i0 + 2 < NB) ? hist[i0 + 2] : 0;
    int c3 = (i0 + 3 < NB) ? hist[i0 + 3] : 0;
    int sum = c0 + c1 + c2 + c3;
    part[tid] = sum;
    __syncthreads();
    for (int off = 1; off < 256; off <<= 1) {
        int t = (tid >= off) ? part[tid - off] : 0;
        __syncthreads();
        part[tid] += t;
        __syncthreads();
    }
    int ex = part[tid] - sum;
    if (i0 + 0 < NB) { lbase[i0 + 0] = ex; ex += c0; }
    if (i0 + 1 < NB) { lbase[i0 + 1] = ex; ex += c1; }
    if (i0 + 2 < NB) { lbase[i0 + 2] = ex; ex += c2; }
    if (i0 + 3 < NB) { lbase[i0 + 3] = ex; ex += c3; }
    __syncthreads();  // part (=gbase) consumed; safe to overwrite
    for (int b = tid; b < NB; b += 256) {
        int h = hist[b];
        gbase[b] = h ? atomicAdd(&bcur[b], h) : 0;
        lcur[b] = 0;
    }
    __syncthreads();
    for (int i = tid; i < nE; i += 256) {
        int s = ei[t0 + i];
        int d = ei[E + t0 + i];
        int b = d >> 7;
        int lo = atomicAdd(&lcur[b], 1);
        int slot = lbase[b] + lo;
        stage[slot] = ((d - (b << 7)) << 17) | s;
        tgt[slot] = gbase[b] + lo;
    }
    __syncthreads();
    for (int i = tid; i < nE; i += 256)
        pp[tgt[i]] = stage[i];
}

// per-bucket: count node degrees from pp, scan -> rowptr/dinv, then scatter col
__global__ __launch_bounds__(256) void k_csr(const int* __restrict__ pp,
                                             const int* __restrict__ bases,
                                             int N, int E,
                                             int* __restrict__ rowptr,
                                             float* __restrict__ dinv,
                                             int* __restrict__ col) {
    __shared__ int lc[BSZ], rp[BSZ], sc[BSZ];
    int b = blockIdx.x, tid = threadIdx.x;
    int n0 = b << 7;
    int base = bases[b];
    int cnt = bases[b + 1] - base;
    if (tid < BSZ) lc[tid] = 0;
    __syncthreads();
    for (int i = tid; i < cnt; i += 256)
        atomicAdd(&lc[pp[base + i] >> 17], 1);
    __syncthreads();
    if (tid < BSZ) sc[tid] = lc[tid];
    __syncthreads();
    for (int off = 1; off < BSZ; off <<= 1) {
        int t = (tid < BSZ && tid >= off) ? sc[tid - off] : 0;
        __syncthreads();
        if (tid < BSZ) sc[tid] += t;
        __syncthreads();
    }
    if (tid < BSZ) {
        int node = n0 + tid;
        int ex = base + sc[tid] - lc[tid];  // exclusive prefix
        rp[tid] = ex;
        if (node < N) {
            rowptr[node] = ex;
            dinv[node] = rsqrtf((float)(lc[tid] + 1));  // +1 self-loop
            if (node == N - 1) rowptr[N] = E;
        }
        lc[tid] = 0;
    }
    __syncthreads();
    for (int i = tid; i < cnt; i += 256) {
        int v = pp[base + i];
        int dl = v >> 17;
        int lo = atomicAdd(&lc[dl], 1);
        col[rp[dl] + lo] = v & 0x1FFFF;
    }
}

// h1s[n][k] = dinv[n] * sum_j x[n][j] * W1[j][k]   (pre-scaled by dinv!)
// lane = node; x via LDS transpose (stride-1 b32 reads); W row wave-uniform -> SGPR
__global__ __launch_bounds__(256) void k_gemm1(const float* __restrict__ x,
                                               const float* __restrict__ W1,
                                               const float* __restrict__ dinv,
                                               float* __restrict__ h1s, int n) {
    __shared__ float xT[KC][256];
    int tid = threadIdx.x;
    int node = blockIdx.x * 256 + tid;
    bool valid = node < n;
    const float* xr = x + (size_t)(valid ? node : (n - 1)) * NFEAT;
    float acc[HID];
#pragma unroll
    for (int k = 0; k < HID; ++k) acc[k] = 0.f;

    for (int c = 0; c < NFEAT / KC; ++c) {
        __syncthreads();  // protect previous chunk's reads
        const float2* src = reinterpret_cast<const float2*>(xr + c * KC);
#pragma unroll
        for (int i = 0; i < KC / 2; ++i) {
            float2 v = src[i];
            xT[2 * i][tid] = v.x;
            xT[2 * i + 1][tid] = v.y;
        }
        __syncthreads();
        const float* wbase = W1 + (size_t)c * KC * HID;
#pragma unroll 5
        for (int j = 0; j < KC; ++j) {
            float xv = xT[j][tid];
            const float4* wr = reinterpret_cast<const float4*>(wbase + (size_t)j * HID);
#pragma unroll
            for (int q = 0; q < HID / 4; ++q) {
                float4 wv = wr[q];  // wave-uniform -> s_load
                acc[4 * q + 0] = fmaf(xv, wv.x, acc[4 * q + 0]);
                acc[4 * q + 1] = fmaf(xv, wv.y, acc[4 * q + 1]);
                acc[4 * q + 2] = fmaf(xv, wv.z, acc[4 * q + 2]);
                acc[4 * q + 3] = fmaf(xv, wv.w, acc[4 * q + 3]);
            }
        }
    }
    if (valid) {
        float dd = dinv[node];
        float4* dst = reinterpret_cast<float4*>(h1s + (size_t)node * HID);
#pragma unroll
        for (int q = 0; q < HID / 4; ++q)
            dst[q] = make_float4(dd * acc[4 * q], dd * acc[4 * q + 1],
                                 dd * acc[4 * q + 2], dd * acc[4 * q + 3]);
    }
}

// CSR gather aggregate layer 1 (pre-scaled h1s), fused bias + tanh.
// 8 lanes/node x float4; 2-edge unroll for MLP. 32 nodes per 256-block.
__global__ __launch_bounds__(256) void k_agg1(const float* __restrict__ h1s,
                                              const int* __restrict__ rowptr,
                                              const int* __restrict__ col,
                                              const float* __restrict__ dinv,
                                              const float* __restrict__ b1,
                                              float* __restrict__ h2, int n) {
    int node = blockIdx.x * 32 + (threadIdx.x >> 3);
    int l = threadIdx.x & 7;  // float4 lane within node
    if (node >= n) return;
    const float4* h4 = reinterpret_cast<const float4*>(h1s);
    int beg = rowptr[node], end = rowptr[node + 1];
    float4 a0 = h4[(size_t)node * 8 + l];  // self-loop term (pre-scaled)
    float4 a1 = make_float4(0.f, 0.f, 0.f, 0.f);
    int j = beg;
    for (; j + 1 < end; j += 2) {
        int s0 = col[j], s1 = col[j + 1];
        float4 v0 = h4[(size_t)s0 * 8 + l];
        float4 v1 = h4[(size_t)s1 * 8 + l];
        a0.x += v0.x; a0.y += v0.y; a0.z += v0.z; a0.w += v0.w;
        a1.x += v1.x; a1.y += v1.y; a1.z += v1.z; a1.w += v1.w;
    }
    if (j < end) {
        float4 v = h4[(size_t)col[j] * 8 + l];
        a0.x += v.x; a0.y += v.y; a0.z += v.z; a0.w += v.w;
    }
    float dd = dinv[node];
    const float4* b4 = reinterpret_cast<const float4*>(b1);
    float4 bv = b4[l];
    float4 r;
    r.x = tanhf(fmaf(dd, a0.x + a1.x, bv.x));
    r.y = tanhf(fmaf(dd, a0.y + a1.y, bv.y));
    r.z = tanhf(fmaf(dd, a0.z + a1.z, bv.z));
    r.w = tanhf(fmaf(dd, a0.w + a1.w, bv.w));
    reinterpret_cast<float4*>(h2)[(size_t)node * 8 + l] = r;
}

// gs[n][c] = dinv[n] * sum_k h2[n][k] * W2[k][c], padded row stride GP=16
__global__ __launch_bounds__(256) void k_gemm2(const float* __restrict__ h2,
                                               const float* __restrict__ W2,
                                               const float* __restrict__ dinv,
                                               float* __restrict__ gs, int n) {
    __shared__ float Ws[HID * NCLS];
    for (int i = threadIdx.x; i < HID * NCLS; i += 256) Ws[i] = W2[i];
    __syncthreads();
    int t = blockIdx.x * 256 + threadIdx.x;
    int node = t >> 4, c = t & 15;
    if (node >= n || c >= NCLS) return;
    const float* hr = h2 + (size_t)node * HID;
    float acc = 0.f;
#pragma unroll
    for (int k = 0; k < HID; ++k) acc = fmaf(hr[k], Ws[k * NCLS + c], acc);
    gs[(size_t)node * GP + c] = acc * dinv[node];
}

// CSR gather aggregate layer 2 (pre-scaled gs, 64B-aligned rows),
// fused bias + log-softmax. 16 lanes/node.
__global__ __launch_bounds__(256) void k_agg2(const float* __restrict__ gs,
                                              const int* __restrict__ rowptr,
                                              const int* __restrict__ col,
                                              const float* __restrict__ dinv,
                                              const float* __restrict__ b2,
                                              float* __restrict__ out, int n) {
    int node = blockIdx.x * 16 + (threadIdx.x >> 4);
    int c = threadIdx.x & 15;
    if (node >= n) return;
    int beg = rowptr[node], end = rowptr[node + 1];
    float acc = 0.f;
    if (c < NCLS) {
        acc = gs[(size_t)node * GP + c];  // self-loop term
        for (int j = beg; j < end; ++j)
            acc += gs[(size_t)col[j] * GP + c];
    }
    float dd = dinv[node];
    float val = (c < NCLS) ? fmaf(dd, acc, b2[c]) : -FLT_MAX;
    float m = val;
#pragma unroll
    for (int off = 1; off < 16; off <<= 1) m = fmaxf(m, __shfl_xor(m, off, 16));
    float p = (c < NCLS) ? expf(val - m) : 0.f;
    float sum = p;
#pragma unroll
    for (int off = 1; off < 16; off <<= 1) sum += __shfl_xor(sum, off, 16);
    if (c < NCLS) out[(size_t)node * NCLS + c] = val - m - logf(sum);
}

static inline size_t align256(size_t b) { return (b + 255) & ~(size_t)255; }

extern "C" void kernel_launch(void* const* d_in, const int* in_sizes, int n_in,
                              void* d_out, int out_size, void* d_ws, size_t ws_size,
                              hipStream_t stream) {
    const float* x  = (const float*)d_in[0];
    const int*   ei = (const int*)d_in[1];
    const float* W1 = (const float*)d_in[2];
    const float* b1 = (const float*)d_in[3];
    const float* W2 = (const float*)d_in[4];
    const float* b2 = (const float*)d_in[5];
    float* out = (float*)d_out;

    const int N = in_sizes[0] / NFEAT;   // 100000
    const int E = in_sizes[1] / 2;       // 3200000
    const int NB = (N + BSZ - 1) / BSZ;  // 782 dst-buckets

    char* p = (char*)d_ws;
    int* bcnt   = (int*)p;  p += align256(1024 * 4);
    int* bases  = (int*)p;  p += align256(1025 * 4);
    int* bcur   = (int*)p;  p += align256(1024 * 4);
    int* rowptr = (int*)p;  p += align256((size_t)(N + 1) * 4);
    int* pp     = (int*)p;  p += align256((size_t)E * 4);   // packed bucketed edges
    int* col    = (int*)p;  p += align256((size_t)E * 4);
    float* dinv = (float*)p; p += align256((size_t)N * 4);
    float* h1s  = (float*)p; p += align256((size_t)N * HID * 4);
    float* h2   = (float*)p; p += align256((size_t)N * HID * 4);
    float* gs   = h1s;  // N*GP floats; h1s dead after k_agg1

    dim3 B(256);
    int nbN = (N + 255) / 256;
    int nT  = (E + TILE - 1) / TILE;

    k_zero_i<<<4, B, 0, stream>>>(bcnt, 1024);
    k_bhist<<<128, B, 0, stream>>>(ei, E, NB, bcnt);
    k_bscan<<<1, 1024, 0, stream>>>(bcnt, NB, E, bases, bcur);
    k_part<<<nT, B, 0, stream>>>(ei, E, NB, bcur, pp);
    k_csr<<<NB, B, 0, stream>>>(pp, bases, N, E, rowptr, dinv, col);

    k_gemm1<<<nbN, B, 0, stream>>>(x, W1, dinv, h1s, N);
    k_agg1<<<(N + 31) / 32, B, 0, stream>>>(h1s, rowptr, col, dinv, b1, h2, N);
    k_gemm2<<<(N * 16 + 255) / 256, B, 0, stream>>>(h2, W2, dinv, gs, N);
    k_agg2<<<(N + 15) / 16, B, 0, stream>>>(gs, rowptr, col, dinv, b2, out, N);
}

// Round 9
// 297.397 us; speedup vs baseline: 3.0937x; 1.0475x over previous
//
#include <hip/hip_runtime.h>
#include <math.h>
#include <float.h>

#define NFEAT 300
#define HID 32
#define NCLS 10
#define GP 16     // padded row stride for layer-2 logits
#define BSZ 128   // nodes per dst-bucket (bucket = dst >> 7)
#define TILE 8192 // edges per k_part tile

__global__ void k_zero_i(int* __restrict__ p, int n) {
    int i = blockIdx.x * 256 + threadIdx.x;
    if (i < n) p[i] = 0;
}

// bucket-level histogram: LDS-privatized, merged via global atomics (782 counters)
__global__ __launch_bounds__(256) void k_bhist(const int* __restrict__ ei, int E, int NB,
                                               int* __restrict__ bcnt) {
    __shared__ int h[1024];
    for (int i = threadIdx.x; i < NB; i += 256) h[i] = 0;
    __syncthreads();
    for (long long i = (long long)blockIdx.x * 256 + threadIdx.x; i < E;
         i += (long long)gridDim.x * 256)
        atomicAdd(&h[ei[E + i] >> 7], 1);
    __syncthreads();
    for (int i = threadIdx.x; i < NB; i += 256) {
        int v = h[i];
        if (v) atomicAdd(&bcnt[i], v);
    }
}

// single-block exclusive scan of bucket counts -> bases (and bcur seed)
__global__ void k_bscan(const int* __restrict__ bcnt, int NB, int E,
                        int* __restrict__ bases, int* __restrict__ bcur) {
    __shared__ int s[1024];
    int tid = threadIdx.x;
    int v = (tid < NB) ? bcnt[tid] : 0;
    s[tid] = v;
    __syncthreads();
    for (int off = 1; off < 1024; off <<= 1) {
        int t = (tid >= off) ? s[tid - off] : 0;
        __syncthreads();
        s[tid] += t;
        __syncthreads();
    }
    if (tid < NB) {
        int ex = s[tid] - v;
        bases[tid] = ex;
        bcur[tid] = ex;
        if (tid == NB - 1) bases[NB] = E;
    }
}

// partition edges into dst-buckets; output packed (dst_local<<17 | src), bucket-contiguous
__global__ __launch_bounds__(256) void k_part(const int* __restrict__ ei, int E, int NB,
                                              int* __restrict__ bcur, int* __restrict__ pp) {
    __shared__ int hist[1024], lbase[1024], gbase[1024], lcur[1024];
    __shared__ int stage[TILE], tgt[TILE];
    int* part = gbase;  // alias: gbase unused until after scan
    int tid = threadIdx.x;
    long long t0 = (long long)blockIdx.x * TILE;
    int nE = (int)(((long long)E - t0 < TILE) ? ((long long)E - t0) : TILE);

    for (int b = tid; b < NB; b += 256) hist[b] = 0;
    __syncthreads();
    for (int i = tid; i < nE; i += 256) {
        int d = ei[E + t0 + i];
        atomicAdd(&hist[d >> 7], 1);
    }
    __syncthreads();
    // exclusive scan hist -> lbase (NB <= 1024), 4 buckets per thread
    int i0 = tid * 4;
    int c0 = (i0 + 0 < NB) ? hist[i0 + 0] : 0;
    int c1 = (i0 + 1 < NB) ? hist[i0 + 1] : 0;
    int c2 = (i0 + 2 < NB) ? hist[i0 + 2] : 0;
    int c3 = (i0 + 3 < NB) ? hist[i0 + 3] : 0;
    int sum = c0 + c1 + c2 + c3;
    part[tid] = sum;
    __syncthreads();
    for (int off = 1; off < 256; off <<= 1) {
        int t = (tid >= off) ? part[tid - off] : 0;
        __syncthreads();
        part[tid] += t;
        __syncthreads();
    }
    int ex = part[tid] - sum;
    if (i0 + 0 < NB) { lbase[i0 + 0] = ex; ex += c0; }
    if (i0 + 1 < NB) { lbase[i0 + 1] = ex; ex += c1; }
    if (i0 + 2 < NB) { lbase[i0 + 2] = ex; ex += c2; }
    if (i0 + 3 < NB) { lbase[i0 + 3] = ex; ex += c3; }
    __syncthreads();  // part (=gbase) consumed; safe to overwrite
    for (int b = tid; b < NB; b += 256) {
        int h = hist[b];
        gbase[b] = h ? atomicAdd(&bcur[b], h) : 0;
        lcur[b] = 0;
    }
    __syncthreads();
    for (int i = tid; i < nE; i += 256) {
        int s = ei[t0 + i];
        int d = ei[E + t0 + i];
        int b = d >> 7;
        int lo = atomicAdd(&lcur[b], 1);
        int slot = lbase[b] + lo;
        stage[slot] = ((d - (b << 7)) << 17) | s;
        tgt[slot] = gbase[b] + lo;
    }
    __syncthreads();
    for (int i = tid; i < nE; i += 256)
        pp[tgt[i]] = stage[i];
}

// per-bucket: count node degrees from pp, scan -> rowptr/dinv, then scatter col
__global__ __launch_bounds__(256) void k_csr(const int* __restrict__ pp,
                                             const int* __restrict__ bases,
                                             int N, int E,
                                             int* __restrict__ rowptr,
                                             float* __restrict__ dinv,
                                             int* __restrict__ col) {
    __shared__ int lc[BSZ], rp[BSZ], sc[BSZ];
    int b = blockIdx.x, tid = threadIdx.x;
    int n0 = b << 7;
    int base = bases[b];
    int cnt = bases[b + 1] - base;
    if (tid < BSZ) lc[tid] = 0;
    __syncthreads();
    for (int i = tid; i < cnt; i += 256)
        atomicAdd(&lc[pp[base + i] >> 17], 1);
    __syncthreads();
    if (tid < BSZ) sc[tid] = lc[tid];
    __syncthreads();
    for (int off = 1; off < BSZ; off <<= 1) {
        int t = (tid < BSZ && tid >= off) ? sc[tid - off] : 0;
        __syncthreads();
        if (tid < BSZ) sc[tid] += t;
        __syncthreads();
    }
    if (tid < BSZ) {
        int node = n0 + tid;
        int ex = base + sc[tid] - lc[tid];  // exclusive prefix
        rp[tid] = ex;
        if (node < N) {
            rowptr[node] = ex;
            dinv[node] = rsqrtf((float)(lc[tid] + 1));  // +1 self-loop
            if (node == N - 1) rowptr[N] = E;
        }
        lc[tid] = 0;
    }
    __syncthreads();
    for (int i = tid; i < cnt; i += 256) {
        int v = pp[base + i];
        int dl = v >> 17;
        int lo = atomicAdd(&lc[dl], 1);
        col[rp[dl] + lo] = v & 0x1FFFF;
    }
}

// h1s[n][k] = dinv[n] * sum_j x[n][j] * W1[j][k]   (pre-scaled by dinv)
// 64 nodes/block, 4 waves; wave q computes k-octet [8q,8q+8) for all 64 nodes.
// lane = node: per-lane float4 x reads (full-line use); W1 row wave-uniform -> s_load.
__global__ __launch_bounds__(256) void k_gemm1(const float* __restrict__ x,
                                               const float* __restrict__ W1,
                                               const float* __restrict__ dinv,
                                               float* __restrict__ h1s, int n) {
    int lane = threadIdx.x & 63;
    int q = __builtin_amdgcn_readfirstlane(threadIdx.x >> 6);  // k-octet index
    int node = blockIdx.x * 64 + lane;
    bool valid = node < n;
    const float4* xr = reinterpret_cast<const float4*>(
        x + (size_t)(valid ? node : (n - 1)) * NFEAT);
    const float* Wq = W1 + q * 8;
    float acc[8];
#pragma unroll
    for (int i = 0; i < 8; ++i) acc[i] = 0.f;
#pragma unroll 5
    for (int c = 0; c < NFEAT / 4; ++c) {  // 75 float4 per row
        float4 xv = xr[c];
        const float* w0 = Wq + (size_t)(4 * c + 0) * HID;
        const float* w1 = Wq + (size_t)(4 * c + 1) * HID;
        const float* w2 = Wq + (size_t)(4 * c + 2) * HID;
        const float* w3 = Wq + (size_t)(4 * c + 3) * HID;
#pragma unroll
        for (int i = 0; i < 8; ++i) {
            acc[i] = fmaf(xv.x, w0[i], acc[i]);
            acc[i] = fmaf(xv.y, w1[i], acc[i]);
            acc[i] = fmaf(xv.z, w2[i], acc[i]);
            acc[i] = fmaf(xv.w, w3[i], acc[i]);
        }
    }
    if (valid) {
        float dd = dinv[node];
        float4* dst = reinterpret_cast<float4*>(h1s + (size_t)node * HID + q * 8);
        dst[0] = make_float4(dd * acc[0], dd * acc[1], dd * acc[2], dd * acc[3]);
        dst[1] = make_float4(dd * acc[4], dd * acc[5], dd * acc[6], dd * acc[7]);
    }
}

// CSR gather aggregate layer 1 (pre-scaled h1s), fused bias + tanh.
// 8 lanes/node x float4; 2-edge unroll for MLP. 32 nodes per 256-block.
__global__ __launch_bounds__(256) void k_agg1(const float* __restrict__ h1s,
                                              const int* __restrict__ rowptr,
                                              const int* __restrict__ col,
                                              const float* __restrict__ dinv,
                                              const float* __restrict__ b1,
                                              float* __restrict__ h2, int n) {
    int node = blockIdx.x * 32 + (threadIdx.x >> 3);
    int l = threadIdx.x & 7;  // float4 lane within node
    if (node >= n) return;
    const float4* h4 = reinterpret_cast<const float4*>(h1s);
    int beg = rowptr[node], end = rowptr[node + 1];
    float4 a0 = h4[(size_t)node * 8 + l];  // self-loop term (pre-scaled)
    float4 a1 = make_float4(0.f, 0.f, 0.f, 0.f);
    int j = beg;
    for (; j + 1 < end; j += 2) {
        int s0 = col[j], s1 = col[j + 1];
        float4 v0 = h4[(size_t)s0 * 8 + l];
        float4 v1 = h4[(size_t)s1 * 8 + l];
        a0.x += v0.x; a0.y += v0.y; a0.z += v0.z; a0.w += v0.w;
        a1.x += v1.x; a1.y += v1.y; a1.z += v1.z; a1.w += v1.w;
    }
    if (j < end) {
        float4 v = h4[(size_t)col[j] * 8 + l];
        a0.x += v.x; a0.y += v.y; a0.z += v.z; a0.w += v.w;
    }
    float dd = dinv[node];
    const float4* b4 = reinterpret_cast<const float4*>(b1);
    float4 bv = b4[l];
    float4 r;
    r.x = tanhf(fmaf(dd, a0.x + a1.x, bv.x));
    r.y = tanhf(fmaf(dd, a0.y + a1.y, bv.y));
    r.z = tanhf(fmaf(dd, a0.z + a1.z, bv.z));
    r.w = tanhf(fmaf(dd, a0.w + a1.w, bv.w));
    reinterpret_cast<float4*>(h2)[(size_t)node * 8 + l] = r;
}

// gs[n][c] = dinv[n] * sum_k h2[n][k] * W2[k][c], padded row stride GP=16
__global__ __launch_bounds__(256) void k_gemm2(const float* __restrict__ h2,
                                               const float* __restrict__ W2,
                                               const float* __restrict__ dinv,
                                               float* __restrict__ gs, int n) {
    __shared__ float Ws[HID * NCLS];
    for (int i = threadIdx.x; i < HID * NCLS; i += 256) Ws[i] = W2[i];
    __syncthreads();
    int t = blockIdx.x * 256 + threadIdx.x;
    int node = t >> 4, c = t & 15;
    if (node >= n || c >= NCLS) return;
    const float* hr = h2 + (size_t)node * HID;
    float acc = 0.f;
#pragma unroll
    for (int k = 0; k < HID; ++k) acc = fmaf(hr[k], Ws[k * NCLS + c], acc);
    gs[(size_t)node * GP + c] = acc * dinv[node];
}

// CSR gather aggregate layer 2 (pre-scaled gs, 64B-aligned rows),
// fused bias + log-softmax. 16 lanes/node.
__global__ __launch_bounds__(256) void k_agg2(const float* __restrict__ gs,
                                              const int* __restrict__ rowptr,
                                              const int* __restrict__ col,
                                              const float* __restrict__ dinv,
                                              const float* __restrict__ b2,
                                              float* __restrict__ out, int n) {
    int node = blockIdx.x * 16 + (threadIdx.x >> 4);
    int c = threadIdx.x & 15;
    if (node >= n) return;
    int beg = rowptr[node], end = rowptr[node + 1];
    float acc = 0.f;
    if (c < NCLS) {
        acc = gs[(size_t)node * GP + c];  // self-loop term
        for (int j = beg; j < end; ++j)
            acc += gs[(size_t)col[j] * GP + c];
    }
    float dd = dinv[node];
    float val = (c < NCLS) ? fmaf(dd, acc, b2[c]) : -FLT_MAX;
    float m = val;
#pragma unroll
    for (int off = 1; off < 16; off <<= 1) m = fmaxf(m, __shfl_xor(m, off, 16));
    float p = (c < NCLS) ? expf(val - m) : 0.f;
    float sum = p;
#pragma unroll
    for (int off = 1; off < 16; off <<= 1) sum += __shfl_xor(sum, off, 16);
    if (c < NCLS) out[(size_t)node * NCLS + c] = val - m - logf(sum);
}

static inline size_t align256(size_t b) { return (b + 255) & ~(size_t)255; }

extern "C" void kernel_launch(void* const* d_in, const int* in_sizes, int n_in,
                              void* d_out, int out_size, void* d_ws, size_t ws_size,
                              hipStream_t stream) {
    const float* x  = (const float*)d_in[0];
    const int*   ei = (const int*)d_in[1];
    const float* W1 = (const float*)d_in[2];
    const float* b1 = (const float*)d_in[3];
    const float* W2 = (const float*)d_in[4];
    const float* b2 = (const float*)d_in[5];
    float* out = (float*)d_out;

    const int N = in_sizes[0] / NFEAT;   // 100000
    const int E = in_sizes[1] / 2;       // 3200000
    const int NB = (N + BSZ - 1) / BSZ;  // 782 dst-buckets

    char* p = (char*)d_ws;
    int* bcnt   = (int*)p;  p += align256(1024 * 4);
    int* bases  = (int*)p;  p += align256(1025 * 4);
    int* bcur   = (int*)p;  p += align256(1024 * 4);
    int* rowptr = (int*)p;  p += align256((size_t)(N + 1) * 4);
    int* pp     = (int*)p;  p += align256((size_t)E * 4);   // packed bucketed edges
    int* col    = (int*)p;  p += align256((size_t)E * 4);
    float* dinv = (float*)p; p += align256((size_t)N * 4);
    float* h1s  = (float*)p; p += align256((size_t)N * HID * 4);
    float* h2   = (float*)p; p += align256((size_t)N * HID * 4);
    float* gs   = h1s;  // N*GP floats; h1s dead after k_agg1

    dim3 B(256);
    int nT = (E + TILE - 1) / TILE;

    k_zero_i<<<4, B, 0, stream>>>(bcnt, 1024);
    k_bhist<<<128, B, 0, stream>>>(ei, E, NB, bcnt);
    k_bscan<<<1, 1024, 0, stream>>>(bcnt, NB, E, bases, bcur);
    k_part<<<nT, B, 0, stream>>>(ei, E, NB, bcur, pp);
    k_csr<<<NB, B, 0, stream>>>(pp, bases, N, E, rowptr, dinv, col);

    k_gemm1<<<(N + 63) / 64, B, 0, stream>>>(x, W1, dinv, h1s, N);
    k_agg1<<<(N + 31) / 32, B, 0, stream>>>(h1s, rowptr, col, dinv, b1, h2, N);
    k_gemm2<<<(N * 16 + 255) / 256, B, 0, stream>>>(h2, W2, dinv, gs, N);
    k_agg2<<<(N + 15) / 16, B, 0, stream>>>(gs, rowptr, col, dinv, b2, out, N);
}

// Round 10
// 259.958 us; speedup vs baseline: 3.5393x; 1.1440x over previous
//
#include <hip/hip_runtime.h>
#include <math.h>
#include <float.h>

#define NFEAT 300
#define HID 32
#define NCLS 10
#define GP 16     // padded row stride for layer-2 logits
#define BSZ 128   // nodes per dst-bucket (bucket = dst >> 7)
#define TILE 8192 // edges per k_part tile

__global__ void k_zero_i(int* __restrict__ p, int n) {
    int i = blockIdx.x * 256 + threadIdx.x;
    if (i < n) p[i] = 0;
}

// bucket-level histogram: LDS-privatized, merged via global atomics (782 counters)
__global__ __launch_bounds__(256) void k_bhist(const int* __restrict__ ei, int E, int NB,
                                               int* __restrict__ bcnt) {
    __shared__ int h[1024];
    for (int i = threadIdx.x; i < NB; i += 256) h[i] = 0;
    __syncthreads();
    for (long long i = (long long)blockIdx.x * 256 + threadIdx.x; i < E;
         i += (long long)gridDim.x * 256)
        atomicAdd(&h[ei[E + i] >> 7], 1);
    __syncthreads();
    for (int i = threadIdx.x; i < NB; i += 256) {
        int v = h[i];
        if (v) atomicAdd(&bcnt[i], v);
    }
}

// single-block exclusive scan of bucket counts -> bases (and bcur seed)
__global__ void k_bscan(const int* __restrict__ bcnt, int NB, int E,
                        int* __restrict__ bases, int* __restrict__ bcur) {
    __shared__ int s[1024];
    int tid = threadIdx.x;
    int v = (tid < NB) ? bcnt[tid] : 0;
    s[tid] = v;
    __syncthreads();
    for (int off = 1; off < 1024; off <<= 1) {
        int t = (tid >= off) ? s[tid - off] : 0;
        __syncthreads();
        s[tid] += t;
        __syncthreads();
    }
    if (tid < NB) {
        int ex = s[tid] - v;
        bases[tid] = ex;
        bcur[tid] = ex;
        if (tid == NB - 1) bases[NB] = E;
    }
}

// partition edges into dst-buckets; output packed (dst_local<<17 | src), bucket-contiguous
__global__ __launch_bounds__(256) void k_part(const int* __restrict__ ei, int E, int NB,
                                              int* __restrict__ bcur, int* __restrict__ pp) {
    __shared__ int hist[1024], lbase[1024], gbase[1024], lcur[1024];
    __shared__ int stage[TILE], tgt[TILE];
    int* part = gbase;  // alias: gbase unused until after scan
    int tid = threadIdx.x;
    long long t0 = (long long)blockIdx.x * TILE;
    int nE = (int)(((long long)E - t0 < TILE) ? ((long long)E - t0) : TILE);

    for (int b = tid; b < NB; b += 256) hist[b] = 0;
    __syncthreads();
    for (int i = tid; i < nE; i += 256) {
        int d = ei[E + t0 + i];
        atomicAdd(&hist[d >> 7], 1);
    }
    __syncthreads();
    // exclusive scan hist -> lbase (NB <= 1024), 4 buckets per thread
    int i0 = tid * 4;
    int c0 = (i0 + 0 < NB) ? hist[i0 + 0] : 0;
    int c1 = (i0 + 1 < NB) ? hist[i0 + 1] : 0;
    int c2 = (i0 + 2 < NB) ? hist[i0 + 2] : 0;
    int c3 = (i0 + 3 < NB) ? hist[i0 + 3] : 0;
    int sum = c0 + c1 + c2 + c3;
    part[tid] = sum;
    __syncthreads();
    for (int off = 1; off < 256; off <<= 1) {
        int t = (tid >= off) ? part[tid - off] : 0;
        __syncthreads();
        part[tid] += t;
        __syncthreads();
    }
    int ex = part[tid] - sum;
    if (i0 + 0 < NB) { lbase[i0 + 0] = ex; ex += c0; }
    if (i0 + 1 < NB) { lbase[i0 + 1] = ex; ex += c1; }
    if (i0 + 2 < NB) { lbase[i0 + 2] = ex; ex += c2; }
    if (i0 + 3 < NB) { lbase[i0 + 3] = ex; ex += c3; }
    __syncthreads();  // part (=gbase) consumed; safe to overwrite
    for (int b = tid; b < NB; b += 256) {
        int h = hist[b];
        gbase[b] = h ? atomicAdd(&bcur[b], h) : 0;
        lcur[b] = 0;
    }
    __syncthreads();
    for (int i = tid; i < nE; i += 256) {
        int s = ei[t0 + i];
        int d = ei[E + t0 + i];
        int b = d >> 7;
        int lo = atomicAdd(&lcur[b], 1);
        int slot = lbase[b] + lo;
        stage[slot] = ((d - (b << 7)) << 17) | s;
        tgt[slot] = gbase[b] + lo;
    }
    __syncthreads();
    for (int i = tid; i < nE; i += 256)
        pp[tgt[i]] = stage[i];
}

// per-bucket: count node degrees from pp, scan -> rowptr/dinv, then scatter col
__global__ __launch_bounds__(256) void k_csr(const int* __restrict__ pp,
                                             const int* __restrict__ bases,
                                             int N, int E,
                                             int* __restrict__ rowptr,
                                             float* __restrict__ dinv,
                                             int* __restrict__ col) {
    __shared__ int lc[BSZ], rp[BSZ], sc[BSZ];
    int b = blockIdx.x, tid = threadIdx.x;
    int n0 = b << 7;
    int base = bases[b];
    int cnt = bases[b + 1] - base;
    if (tid < BSZ) lc[tid] = 0;
    __syncthreads();
    for (int i = tid; i < cnt; i += 256)
        atomicAdd(&lc[pp[base + i] >> 17], 1);
    __syncthreads();
    if (tid < BSZ) sc[tid] = lc[tid];
    __syncthreads();
    for (int off = 1; off < BSZ; off <<= 1) {
        int t = (tid < BSZ && tid >= off) ? sc[tid - off] : 0;
        __syncthreads();
        if (tid < BSZ) sc[tid] += t;
        __syncthreads();
    }
    if (tid < BSZ) {
        int node = n0 + tid;
        int ex = base + sc[tid] - lc[tid];  // exclusive prefix
        rp[tid] = ex;
        if (node < N) {
            rowptr[node] = ex;
            dinv[node] = rsqrtf((float)(lc[tid] + 1));  // +1 self-loop
            if (node == N - 1) rowptr[N] = E;
        }
        lc[tid] = 0;
    }
    __syncthreads();
    for (int i = tid; i < cnt; i += 256) {
        int v = pp[base + i];
        int dl = v >> 17;
        int lo = atomicAdd(&lc[dl], 1);
        col[rp[dl] + lo] = v & 0x1FFFF;
    }
}

// h1s[n][k] = dinv[n] * sum_j x[n][j] * W1[j][k]   (pre-scaled by dinv)
// 64 nodes/block, 4 waves; wave q computes k-octet [8q,8q+8) for all 64 nodes.
__global__ __launch_bounds__(256) void k_gemm1(const float* __restrict__ x,
                                               const float* __restrict__ W1,
                                               const float* __restrict__ dinv,
                                               float* __restrict__ h1s, int n) {
    int lane = threadIdx.x & 63;
    int q = __builtin_amdgcn_readfirstlane(threadIdx.x >> 6);  // k-octet index
    int node = blockIdx.x * 64 + lane;
    bool valid = node < n;
    const float4* xr = reinterpret_cast<const float4*>(
        x + (size_t)(valid ? node : (n - 1)) * NFEAT);
    const float* Wq = W1 + q * 8;
    float acc[8];
#pragma unroll
    for (int i = 0; i < 8; ++i) acc[i] = 0.f;
#pragma unroll 5
    for (int c = 0; c < NFEAT / 4; ++c) {  // 75 float4 per row
        float4 xv = xr[c];
        const float* w0 = Wq + (size_t)(4 * c + 0) * HID;
        const float* w1 = Wq + (size_t)(4 * c + 1) * HID;
        const float* w2 = Wq + (size_t)(4 * c + 2) * HID;
        const float* w3 = Wq + (size_t)(4 * c + 3) * HID;
#pragma unroll
        for (int i = 0; i < 8; ++i) {
            acc[i] = fmaf(xv.x, w0[i], acc[i]);
            acc[i] = fmaf(xv.y, w1[i], acc[i]);
            acc[i] = fmaf(xv.z, w2[i], acc[i]);
            acc[i] = fmaf(xv.w, w3[i], acc[i]);
        }
    }
    if (valid) {
        float dd = dinv[node];
        float4* dst = reinterpret_cast<float4*>(h1s + (size_t)node * HID + q * 8);
        dst[0] = make_float4(dd * acc[0], dd * acc[1], dd * acc[2], dd * acc[3]);
        dst[1] = make_float4(dd * acc[4], dd * acc[5], dd * acc[6], dd * acc[7]);
    }
}

// CSR gather aggregate layer 1 (pre-scaled h1s), fused bias + tanh.
// 8 lanes/node x float4; 4-edge unroll (32 gathers in flight/wave).
__global__ __launch_bounds__(256) void k_agg1(const float* __restrict__ h1s,
                                              const int* __restrict__ rowptr,
                                              const int* __restrict__ col,
                                              const float* __restrict__ dinv,
                                              const float* __restrict__ b1,
                                              float* __restrict__ h2, int n) {
    int node = blockIdx.x * 32 + (threadIdx.x >> 3);
    int l = threadIdx.x & 7;  // float4 lane within node
    if (node >= n) return;
    const float4* h4 = reinterpret_cast<const float4*>(h1s);
    int beg = rowptr[node], end = rowptr[node + 1];
    float4 a0 = h4[(size_t)node * 8 + l];  // self-loop term (pre-scaled)
    float4 a1 = make_float4(0.f, 0.f, 0.f, 0.f);
    float4 a2 = make_float4(0.f, 0.f, 0.f, 0.f);
    float4 a3 = make_float4(0.f, 0.f, 0.f, 0.f);
    int j = beg;
    for (; j + 3 < end; j += 4) {
        int s0 = col[j], s1 = col[j + 1], s2 = col[j + 2], s3 = col[j + 3];
        float4 v0 = h4[(size_t)s0 * 8 + l];
        float4 v1 = h4[(size_t)s1 * 8 + l];
        float4 v2 = h4[(size_t)s2 * 8 + l];
        float4 v3 = h4[(size_t)s3 * 8 + l];
        a0.x += v0.x; a0.y += v0.y; a0.z += v0.z; a0.w += v0.w;
        a1.x += v1.x; a1.y += v1.y; a1.z += v1.z; a1.w += v1.w;
        a2.x += v2.x; a2.y += v2.y; a2.z += v2.z; a2.w += v2.w;
        a3.x += v3.x; a3.y += v3.y; a3.z += v3.z; a3.w += v3.w;
    }
    for (; j < end; ++j) {
        float4 v = h4[(size_t)col[j] * 8 + l];
        a0.x += v.x; a0.y += v.y; a0.z += v.z; a0.w += v.w;
    }
    float dd = dinv[node];
    const float4* b4 = reinterpret_cast<const float4*>(b1);
    float4 bv = b4[l];
    float4 r;
    r.x = tanhf(fmaf(dd, (a0.x + a1.x) + (a2.x + a3.x), bv.x));
    r.y = tanhf(fmaf(dd, (a0.y + a1.y) + (a2.y + a3.y), bv.y));
    r.z = tanhf(fmaf(dd, (a0.z + a1.z) + (a2.z + a3.z), bv.z));
    r.w = tanhf(fmaf(dd, (a0.w + a1.w) + (a2.w + a3.w), bv.w));
    reinterpret_cast<float4*>(h2)[(size_t)node * 8 + l] = r;
}

// gs[n][c] = dinv[n] * sum_k h2[n][k] * W2[k][c], padded row stride GP=16
__global__ __launch_bounds__(256) void k_gemm2(const float* __restrict__ h2,
                                               const float* __restrict__ W2,
                                               const float* __restrict__ dinv,
                                               float* __restrict__ gs, int n) {
    __shared__ float Ws[HID * NCLS];
    for (int i = threadIdx.x; i < HID * NCLS; i += 256) Ws[i] = W2[i];
    __syncthreads();
    int t = blockIdx.x * 256 + threadIdx.x;
    int node = t >> 4, c = t & 15;
    if (node >= n || c >= NCLS) return;
    const float* hr = h2 + (size_t)node * HID;
    float acc = 0.f;
#pragma unroll
    for (int k = 0; k < HID; ++k) acc = fmaf(hr[k], Ws[k * NCLS + c], acc);
    gs[(size_t)node * GP + c] = acc * dinv[node];
}

// CSR gather aggregate layer 2 (pre-scaled gs), fused bias + log-softmax.
// 4 lanes/node x float4 (one gs row = 4 float4s); 2-edge unroll.
__global__ __launch_bounds__(256) void k_agg2(const float* __restrict__ gs,
                                              const int* __restrict__ rowptr,
                                              const int* __restrict__ col,
                                              const float* __restrict__ dinv,
                                              const float* __restrict__ b2,
                                              float* __restrict__ out, int n) {
    int node = blockIdx.x * 64 + (threadIdx.x >> 2);
    int l = threadIdx.x & 3;  // float4 lane: classes 4l..4l+3
    if (node >= n) return;
    const float4* g4 = reinterpret_cast<const float4*>(gs);
    int beg = rowptr[node], end = rowptr[node + 1];
    float4 a0 = g4[(size_t)node * 4 + l];  // self-loop term (pre-scaled)
    float4 a1 = make_float4(0.f, 0.f, 0.f, 0.f);
    int j = beg;
    for (; j + 1 < end; j += 2) {
        int s0 = col[j], s1 = col[j + 1];
        float4 v0 = g4[(size_t)s0 * 4 + l];
        float4 v1 = g4[(size_t)s1 * 4 + l];
        a0.x += v0.x; a0.y += v0.y; a0.z += v0.z; a0.w += v0.w;
        a1.x += v1.x; a1.y += v1.y; a1.z += v1.z; a1.w += v1.w;
    }
    if (j < end) {
        float4 v = g4[(size_t)col[j] * 4 + l];
        a0.x += v.x; a0.y += v.y; a0.z += v.z; a0.w += v.w;
    }
    float dd = dinv[node];
    int c0 = 4 * l;
    float val[4];
    float av[4] = {a0.x + a1.x, a0.y + a1.y, a0.z + a1.z, a0.w + a1.w};
#pragma unroll
    for (int i = 0; i < 4; ++i) {
        int c = c0 + i;
        val[i] = (c < NCLS) ? fmaf(dd, av[i], b2[c]) : -FLT_MAX;
    }
    float m = fmaxf(fmaxf(val[0], val[1]), fmaxf(val[2], val[3]));
    m = fmaxf(m, __shfl_xor(m, 1, 4));
    m = fmaxf(m, __shfl_xor(m, 2, 4));
    float s = 0.f;
#pragma unroll
    for (int i = 0; i < 4; ++i)
        if (c0 + i < NCLS) s += expf(val[i] - m);
    s += __shfl_xor(s, 1, 4);
    s += __shfl_xor(s, 2, 4);
    float ls = m + logf(s);
    float* orow = out + (size_t)node * NCLS;
#pragma unroll
    for (int i = 0; i < 4; ++i)
        if (c0 + i < NCLS) orow[c0 + i] = val[i] - ls;
}

static inline size_t align256(size_t b) { return (b + 255) & ~(size_t)255; }

extern "C" void kernel_launch(void* const* d_in, const int* in_sizes, int n_in,
                              void* d_out, int out_size, void* d_ws, size_t ws_size,
                              hipStream_t stream) {
    const float* x  = (const float*)d_in[0];
    const int*   ei = (const int*)d_in[1];
    const float* W1 = (const float*)d_in[2];
    const float* b1 = (const float*)d_in[3];
    const float* W2 = (const float*)d_in[4];
    const float* b2 = (const float*)d_in[5];
    float* out = (float*)d_out;

    const int N = in_sizes[0] / NFEAT;   // 100000
    const int E = in_sizes[1] / 2;       // 3200000
    const int NB = (N + BSZ - 1) / BSZ;  // 782 dst-buckets

    char* p = (char*)d_ws;
    int* bcnt   = (int*)p;  p += align256(1024 * 4);
    int* bases  = (int*)p;  p += align256(1025 * 4);
    int* bcur   = (int*)p;  p += align256(1024 * 4);
    int* rowptr = (int*)p;  p += align256((size_t)(N + 1) * 4);
    int* pp     = (int*)p;  p += align256((size_t)E * 4);   // packed bucketed edges
    int* col    = (int*)p;  p += align256((size_t)E * 4);
    float* dinv = (float*)p; p += align256((size_t)N * 4);
    float* h1s  = (float*)p; p += align256((size_t)N * HID * 4);
    float* h2   = (float*)p; p += align256((size_t)N * HID * 4);
    float* gs   = h1s;  // N*GP floats; h1s dead after k_agg1

    dim3 B(256);
    int nT = (E + TILE - 1) / TILE;

    k_zero_i<<<4, B, 0, stream>>>(bcnt, 1024);
    k_bhist<<<128, B, 0, stream>>>(ei, E, NB, bcnt);
    k_bscan<<<1, 1024, 0, stream>>>(bcnt, NB, E, bases, bcur);
    k_part<<<nT, B, 0, stream>>>(ei, E, NB, bcur, pp);
    k_csr<<<NB, B, 0, stream>>>(pp, bases, N, E, rowptr, dinv, col);

    k_gemm1<<<(N + 63) / 64, B, 0, stream>>>(x, W1, dinv, h1s, N);
    k_agg1<<<(N + 31) / 32, B, 0, stream>>>(h1s, rowptr, col, dinv, b1, h2, N);
    k_gemm2<<<(N * 16 + 255) / 256, B, 0, stream>>>(h2, W2, dinv, gs, N);
    k_agg2<<<(N + 63) / 64, B, 0, stream>>>(gs, rowptr, col, dinv, b2, out, N);
}